// Round 1
// baseline (748.341 us; speedup 1.0000x reference)
//
#include <hip/hip_runtime.h>
#include <hip/hip_bf16.h>

#define NEG 0.2f

// ---------------- CSR build ----------------
__global__ void k_hist(const int* __restrict__ dst, int* __restrict__ cnt, int E){
  int i = blockIdx.x*blockDim.x + threadIdx.x;
  if (i < E) atomicAdd(&cnt[dst[i]], 1);
}

__global__ void k_scanA(const int* __restrict__ cnt, int* __restrict__ exout,
                        int* __restrict__ bsum, int n){
  __shared__ int sd[256];
  int t = threadIdx.x, b = blockIdx.x;
  int base = b*1024 + t*4;
  int v0 = (base+0<n) ? cnt[base+0] : 0;
  int v1 = (base+1<n) ? cnt[base+1] : 0;
  int v2 = (base+2<n) ? cnt[base+2] : 0;
  int v3 = (base+3<n) ? cnt[base+3] : 0;
  int s = v0+v1+v2+v3;
  sd[t] = s; __syncthreads();
  for (int off=1; off<256; off<<=1){
    int x = (t>=off) ? sd[t-off] : 0;
    __syncthreads();
    sd[t] += x;
    __syncthreads();
  }
  int ex = sd[t] - s;
  if (t==255) bsum[b] = sd[t];
  if (base+0<n) exout[base+0]=ex; ex+=v0;
  if (base+1<n) exout[base+1]=ex; ex+=v1;
  if (base+2<n) exout[base+2]=ex; ex+=v2;
  if (base+3<n) exout[base+3]=ex;
}

__global__ void k_scanB(const int* __restrict__ bsum, int* __restrict__ boff,
                        int* __restrict__ rowptr, int B, int n){
  if (threadIdx.x==0){
    int run=0;
    for (int b=0;b<B;++b){ int t=bsum[b]; boff[b]=run; run+=t; }
    rowptr[n]=run;
  }
}

__global__ void k_scanC(int* __restrict__ rowptr, const int* __restrict__ boff, int n){
  int i = blockIdx.x*blockDim.x + threadIdx.x;
  if (i<n) rowptr[i] += boff[i>>10];
}

__global__ void k_scatter(const int* __restrict__ src, const int* __restrict__ dst,
                          const int* __restrict__ rowptr, int* __restrict__ fill,
                          int* __restrict__ csr, int E){
  int i = blockIdx.x*blockDim.x + threadIdx.x;
  if (i<E){
    int d = dst[i];
    int p = atomicAdd(&fill[d], 1);
    csr[rowptr[d]+p] = src[i];
  }
}

// ---------------- GEMM (x@W) fused with attention dots ----------------
// block: 256 threads, 64 nodes/block, thread tile = 4 nodes x 8 cols
__global__ __launch_bounds__(256) void k_gemm_att(
    const float* __restrict__ xin, const float* __restrict__ W,
    const float* __restrict__ atts, const float* __restrict__ attd,
    float* __restrict__ h, float* __restrict__ as_, float* __restrict__ ad_, int n)
{
  __shared__ float xs[64*129];
  int t = threadIdx.x;
  int base = blockIdx.x*64;
  for (int i=t; i<64*128; i+=256){
    int r = i>>7, c = i&127;
    xs[r*129+c] = (base+r < n) ? xin[(size_t)(base+r)*128 + c] : 0.f;
  }
  __syncthreads();
  int cx = t & 15, rn = t >> 4;
  int c0 = cx*8;
  int r0 = rn*4;
  float acc[4][8];
  #pragma unroll
  for (int r=0;r<4;++r)
    #pragma unroll
    for (int j=0;j<8;++j) acc[r][j]=0.f;
  const float4* W4 = reinterpret_cast<const float4*>(W);
  for (int k=0;k<128;++k){
    float4 wa = W4[(k*128 + c0)>>2];
    float4 wb = W4[(k*128 + c0 + 4)>>2];
    float w[8] = {wa.x,wa.y,wa.z,wa.w,wb.x,wb.y,wb.z,wb.w};
    #pragma unroll
    for (int r=0;r<4;++r){
      float xk = xs[(r0+r)*129 + k];
      #pragma unroll
      for (int j=0;j<8;++j) acc[r][j] = fmaf(xk, w[j], acc[r][j]);
    }
  }
  int head = cx>>2, q = cx&3;
  #pragma unroll
  for (int r=0;r<4;++r){
    int node = base + r0 + r;
    float ps=0.f, pd=0.f;
    #pragma unroll
    for (int j=0;j<8;++j){
      float av = atts[head*32 + q*8 + j];
      float dv = attd[head*32 + q*8 + j];
      ps = fmaf(acc[r][j], av, ps);
      pd = fmaf(acc[r][j], dv, pd);
    }
    ps += __shfl_xor(ps,1); ps += __shfl_xor(ps,2);
    pd += __shfl_xor(pd,1); pd += __shfl_xor(pd,2);
    if (node < n){
      float4 ha = make_float4(acc[r][0],acc[r][1],acc[r][2],acc[r][3]);
      float4 hb = make_float4(acc[r][4],acc[r][5],acc[r][6],acc[r][7]);
      float4* H4 = reinterpret_cast<float4*>(h + (size_t)node*128 + c0);
      H4[0]=ha; H4[1]=hb;
      if (q==0){ as_[node*4+head]=ps; ad_[node*4+head]=pd; }
    }
  }
}

// ---------------- per-node softmax-aggregation (1 wave = 1 node) ----------------
__global__ __launch_bounds__(256) void k_aggr(
    const float* __restrict__ h, const float* __restrict__ as_,
    const float* __restrict__ ad_, const int* __restrict__ rowptr,
    const int* __restrict__ csr, const float* __restrict__ bias,
    float* __restrict__ out, int n)
{
  int wid = (int)((blockIdx.x*(size_t)blockDim.x + threadIdx.x) >> 6);
  int lane = threadIdx.x & 63;
  if (wid >= n) return;
  int head = lane >> 4;
  int c0 = lane*2;
  float adn = ad_[wid*4 + head];
  int beg = rowptr[wid], end = rowptr[wid+1];
  float acc0=0.f, acc1=0.f, z=0.f;
  for (int i=beg; i<end; ++i){
    int s = csr[i];
    float e = as_[s*4 + head] + adn;
    e = (e > 0.f) ? e : NEG*e;
    float ee = __expf(e);
    z += ee;
    const float2 hv = *reinterpret_cast<const float2*>(h + (size_t)s*128 + c0);
    acc0 = fmaf(ee, hv.x, acc0);
    acc1 = fmaf(ee, hv.y, acc1);
  }
  float o0, o1;
  if (end > beg){
    o0 = acc0/z + bias[c0];
    o1 = acc1/z + bias[c0+1];
  } else {
    o0 = bias[c0]; o1 = bias[c0+1];
  }
  out[(size_t)wid*128 + c0]   = fmaxf(o0, 0.f);
  out[(size_t)wid*128 + c0+1] = fmaxf(o1, 0.f);
}

// ---------------- fused 2-layer MLP ----------------
__global__ __launch_bounds__(256) void k_mlp(
    const float* __restrict__ x, const float* __restrict__ Wm1, const float* __restrict__ bm1,
    const float* __restrict__ Wm2, const float* __restrict__ bm2,
    float* __restrict__ out, int n)
{
  __shared__ float xs[64*129];
  __shared__ float w1s[128*32];
  __shared__ float hs[64*33];
  __shared__ float w2s[32*16];
  __shared__ float b1s[32];
  __shared__ float b2s[16];
  int t = threadIdx.x;
  int base = blockIdx.x*64;
  for (int i=t; i<64*128; i+=256){
    int r=i>>7, c=i&127;
    xs[r*129+c] = (base+r<n) ? x[(size_t)(base+r)*128+c] : 0.f;
  }
  for (int i=t; i<128*32; i+=256) w1s[i]=Wm1[i];
  for (int i=t; i<32*16;  i+=256) w2s[i]=Wm2[i];
  if (t<32) b1s[t]=bm1[t];
  if (t<16) b2s[t]=bm2[t];
  __syncthreads();
  int l = t&63, g = t>>6;
  float hid[8];
  #pragma unroll
  for (int j=0;j<8;++j) hid[j]=0.f;
  for (int k=0;k<128;++k){
    float xk = xs[l*129+k];
    #pragma unroll
    for (int j=0;j<8;++j) hid[j] = fmaf(xk, w1s[k*32 + g*8 + j], hid[j]);
  }
  #pragma unroll
  for (int j=0;j<8;++j) hs[l*33 + g*8 + j] = fmaxf(hid[j] + b1s[g*8+j], 0.f);
  __syncthreads();
  float o[4] = {0.f,0.f,0.f,0.f};
  for (int k=0;k<32;++k){
    float xv = hs[l*33+k];
    #pragma unroll
    for (int j=0;j<4;++j) o[j] = fmaf(xv, w2s[k*16 + g*4 + j], o[j]);
  }
  int node = base + l;
  if (node < n){
    #pragma unroll
    for (int j=0;j<4;++j) out[(size_t)node*16 + g*4 + j] = o[j] + b2s[g*4+j];
  }
}

extern "C" void kernel_launch(void* const* d_in, const int* in_sizes, int n_in,
                              void* d_out, int out_size, void* d_ws, size_t ws_size,
                              hipStream_t stream)
{
  const float* x   = (const float*)d_in[0];
  const int*   ei  = (const int*)  d_in[1];
  const float* W0  = (const float*)d_in[2];
  const float* as0 = (const float*)d_in[3];
  const float* ad0 = (const float*)d_in[4];
  const float* b0  = (const float*)d_in[5];
  const float* W1  = (const float*)d_in[6];
  const float* as1 = (const float*)d_in[7];
  const float* ad1 = (const float*)d_in[8];
  const float* b1  = (const float*)d_in[9];
  const float* Wm1 = (const float*)d_in[10];
  const float* bm1 = (const float*)d_in[11];
  const float* Wm2 = (const float*)d_in[12];
  const float* bm2 = (const float*)d_in[13];
  int N = in_sizes[0]/128;
  int E = in_sizes[1]/2;
  const int* srcI = ei;
  const int* dstI = ei + E;

  char* ws = (char*)d_ws;
  size_t off = 0;
  auto alloc = [&](size_t bytes)->void*{
    void* p = ws + off; off += (bytes + 255) & ~(size_t)255; return p;
  };
  float* hbuf  = (float*)alloc((size_t)N*128*4);
  float* xbuf  = (float*)alloc((size_t)N*128*4);
  float* asb   = (float*)alloc((size_t)N*4*4);
  float* adb   = (float*)alloc((size_t)N*4*4);
  int* rowptr  = (int*)alloc((size_t)(N+1)*4);
  int* cnt     = (int*)alloc((size_t)N*4);
  int* fill    = (int*)alloc((size_t)N*4);
  int* bsum    = (int*)alloc(4096);
  int* boff    = (int*)alloc(4096);
  int* csr     = (int*)alloc((size_t)E*4);
  (void)ws_size; (void)n_in; (void)out_size;

  int B = (N+1023)/1024;
  hipMemsetAsync(cnt,  0, (size_t)N*4, stream);
  hipMemsetAsync(fill, 0, (size_t)N*4, stream);
  int gE = (E+255)/256;
  k_hist   <<<gE,256,0,stream>>>(dstI, cnt, E);
  k_scanA  <<<B, 256,0,stream>>>(cnt, rowptr, bsum, N);
  k_scanB  <<<1, 64, 0,stream>>>(bsum, boff, rowptr, B, N);
  k_scanC  <<<(N+255)/256,256,0,stream>>>(rowptr, boff, N);
  k_scatter<<<gE,256,0,stream>>>(srcI, dstI, rowptr, fill, csr, E);

  int gG = (N+63)/64;
  int gA = (int)(((size_t)N*64 + 255)/256);
  k_gemm_att<<<gG,256,0,stream>>>(x,    W0, as0, ad0, hbuf, asb, adb, N);
  k_aggr    <<<gA,256,0,stream>>>(hbuf, asb, adb, rowptr, csr, b0, xbuf, N);
  k_gemm_att<<<gG,256,0,stream>>>(xbuf, W1, as1, ad1, hbuf, asb, adb, N);
  k_aggr    <<<gA,256,0,stream>>>(hbuf, asb, adb, rowptr, csr, b1, xbuf, N);
  k_mlp     <<<gG,256,0,stream>>>(xbuf, Wm1, bm1, Wm2, bm2, (float*)d_out, N);
}

// Round 2
// 654.508 us; speedup vs baseline: 1.1434x; 1.1434x over previous
//
#include <hip/hip_runtime.h>
#include <hip/hip_bf16.h>

#define NEG 0.2f

// ---------------- CSR build ----------------
__global__ void k_hist(const int* __restrict__ dst, int* __restrict__ cnt, int E){
  int i = blockIdx.x*blockDim.x + threadIdx.x;
  if (i < E) atomicAdd(&cnt[dst[i]], 1);
}

__global__ void k_scanA(const int* __restrict__ cnt, int* __restrict__ exout,
                        int* __restrict__ bsum, int n){
  __shared__ int sd[256];
  int t = threadIdx.x, b = blockIdx.x;
  int base = b*1024 + t*4;
  int v0 = (base+0<n) ? cnt[base+0] : 0;
  int v1 = (base+1<n) ? cnt[base+1] : 0;
  int v2 = (base+2<n) ? cnt[base+2] : 0;
  int v3 = (base+3<n) ? cnt[base+3] : 0;
  int s = v0+v1+v2+v3;
  sd[t] = s; __syncthreads();
  for (int off=1; off<256; off<<=1){
    int x = (t>=off) ? sd[t-off] : 0;
    __syncthreads();
    sd[t] += x;
    __syncthreads();
  }
  int ex = sd[t] - s;
  if (t==255) bsum[b] = sd[t];
  if (base+0<n) exout[base+0]=ex; ex+=v0;
  if (base+1<n) exout[base+1]=ex; ex+=v1;
  if (base+2<n) exout[base+2]=ex; ex+=v2;
  if (base+3<n) exout[base+3]=ex;
}

__global__ void k_scanB(const int* __restrict__ bsum, int* __restrict__ boff,
                        int* __restrict__ rowptr, int B, int n){
  if (threadIdx.x==0){
    int run=0;
    for (int b=0;b<B;++b){ int t=bsum[b]; boff[b]=run; run+=t; }
    rowptr[n]=run;
  }
}

__global__ void k_scanC(int* __restrict__ rowptr, const int* __restrict__ boff, int n){
  int i = blockIdx.x*blockDim.x + threadIdx.x;
  if (i<n) rowptr[i] += boff[i>>10];
}

__global__ void k_scatter(const int* __restrict__ src, const int* __restrict__ dst,
                          const int* __restrict__ rowptr, int* __restrict__ fill,
                          int* __restrict__ csr, int E){
  int i = blockIdx.x*blockDim.x + threadIdx.x;
  if (i<E){
    int d = dst[i];
    int p = atomicAdd(&fill[d], 1);
    csr[rowptr[d]+p] = src[i];
  }
}

// ---------------- GEMM (x@W) fused with attention dots ----------------
__global__ __launch_bounds__(256) void k_gemm_att(
    const float* __restrict__ xin, const float* __restrict__ W,
    const float* __restrict__ atts, const float* __restrict__ attd,
    float* __restrict__ h, float* __restrict__ as_, float* __restrict__ ad_, int n)
{
  __shared__ float xs[64*129];
  int t = threadIdx.x;
  int base = blockIdx.x*64;
  for (int i=t; i<64*128; i+=256){
    int r = i>>7, c = i&127;
    xs[r*129+c] = (base+r < n) ? xin[(size_t)(base+r)*128 + c] : 0.f;
  }
  __syncthreads();
  int cx = t & 15, rn = t >> 4;
  int c0 = cx*8;
  int r0 = rn*4;
  float acc[4][8];
  #pragma unroll
  for (int r=0;r<4;++r)
    #pragma unroll
    for (int j=0;j<8;++j) acc[r][j]=0.f;
  const float4* W4 = reinterpret_cast<const float4*>(W);
  for (int k=0;k<128;++k){
    float4 wa = W4[(k*128 + c0)>>2];
    float4 wb = W4[(k*128 + c0 + 4)>>2];
    float w[8] = {wa.x,wa.y,wa.z,wa.w,wb.x,wb.y,wb.z,wb.w};
    #pragma unroll
    for (int r=0;r<4;++r){
      float xk = xs[(r0+r)*129 + k];
      #pragma unroll
      for (int j=0;j<8;++j) acc[r][j] = fmaf(xk, w[j], acc[r][j]);
    }
  }
  int head = cx>>2, q = cx&3;
  #pragma unroll
  for (int r=0;r<4;++r){
    int node = base + r0 + r;
    float ps=0.f, pd=0.f;
    #pragma unroll
    for (int j=0;j<8;++j){
      float av = atts[head*32 + q*8 + j];
      float dv = attd[head*32 + q*8 + j];
      ps = fmaf(acc[r][j], av, ps);
      pd = fmaf(acc[r][j], dv, pd);
    }
    ps += __shfl_xor(ps,1); ps += __shfl_xor(ps,2);
    pd += __shfl_xor(pd,1); pd += __shfl_xor(pd,2);
    if (node < n){
      float4 ha = make_float4(acc[r][0],acc[r][1],acc[r][2],acc[r][3]);
      float4 hb = make_float4(acc[r][4],acc[r][5],acc[r][6],acc[r][7]);
      float4* H4 = reinterpret_cast<float4*>(h + (size_t)node*128 + c0);
      H4[0]=ha; H4[1]=hb;
      if (q==0){ as_[node*4+head]=ps; ad_[node*4+head]=pd; }
    }
  }
}

// ---------------- per-node softmax-aggregation (1 wave = 1 node) ----------------
// R2: 4x edge unroll with batched independent loads for memory-level parallelism.
__global__ __launch_bounds__(256) void k_aggr(
    const float* __restrict__ h, const float* __restrict__ as_,
    const float* __restrict__ ad_, const int* __restrict__ rowptr,
    const int* __restrict__ csr, const float* __restrict__ bias,
    float* __restrict__ out, int n)
{
  int wid = (int)((blockIdx.x*(size_t)blockDim.x + threadIdx.x) >> 6);
  int lane = threadIdx.x & 63;
  if (wid >= n) return;
  int head = lane >> 4;
  int c0 = lane*2;
  float adn = ad_[wid*4 + head];
  int beg = rowptr[wid], end = rowptr[wid+1];
  float acc0=0.f, acc1=0.f, z=0.f;
  int i = beg;
  for (; i+4 <= end; i += 4){
    int s0 = csr[i+0];
    int s1 = csr[i+1];
    int s2 = csr[i+2];
    int s3 = csr[i+3];
    float e0 = as_[s0*4+head];
    float e1 = as_[s1*4+head];
    float e2 = as_[s2*4+head];
    float e3 = as_[s3*4+head];
    float2 h0 = *reinterpret_cast<const float2*>(h + (size_t)s0*128 + c0);
    float2 h1 = *reinterpret_cast<const float2*>(h + (size_t)s1*128 + c0);
    float2 h2 = *reinterpret_cast<const float2*>(h + (size_t)s2*128 + c0);
    float2 h3 = *reinterpret_cast<const float2*>(h + (size_t)s3*128 + c0);
    e0 += adn; e1 += adn; e2 += adn; e3 += adn;
    e0 = (e0>0.f)?e0:NEG*e0;
    e1 = (e1>0.f)?e1:NEG*e1;
    e2 = (e2>0.f)?e2:NEG*e2;
    e3 = (e3>0.f)?e3:NEG*e3;
    float x0 = __expf(e0);
    float x1 = __expf(e1);
    float x2 = __expf(e2);
    float x3 = __expf(e3);
    z += (x0+x1)+(x2+x3);
    acc0 = fmaf(x0, h0.x, acc0); acc1 = fmaf(x0, h0.y, acc1);
    acc0 = fmaf(x1, h1.x, acc0); acc1 = fmaf(x1, h1.y, acc1);
    acc0 = fmaf(x2, h2.x, acc0); acc1 = fmaf(x2, h2.y, acc1);
    acc0 = fmaf(x3, h3.x, acc0); acc1 = fmaf(x3, h3.y, acc1);
  }
  for (; i < end; ++i){
    int s = csr[i];
    float e = as_[s*4 + head] + adn;
    e = (e > 0.f) ? e : NEG*e;
    float ee = __expf(e);
    z += ee;
    const float2 hv = *reinterpret_cast<const float2*>(h + (size_t)s*128 + c0);
    acc0 = fmaf(ee, hv.x, acc0);
    acc1 = fmaf(ee, hv.y, acc1);
  }
  float2 o;
  if (end > beg){
    float rz = 1.f/z;
    o.x = acc0*rz + bias[c0];
    o.y = acc1*rz + bias[c0+1];
  } else {
    o.x = bias[c0]; o.y = bias[c0+1];
  }
  o.x = fmaxf(o.x, 0.f);
  o.y = fmaxf(o.y, 0.f);
  *reinterpret_cast<float2*>(out + (size_t)wid*128 + c0) = o;
}

// ---------------- fused 2-layer MLP ----------------
__global__ __launch_bounds__(256) void k_mlp(
    const float* __restrict__ x, const float* __restrict__ Wm1, const float* __restrict__ bm1,
    const float* __restrict__ Wm2, const float* __restrict__ bm2,
    float* __restrict__ out, int n)
{
  __shared__ float xs[64*129];
  __shared__ float w1s[128*32];
  __shared__ float hs[64*33];
  __shared__ float w2s[32*16];
  __shared__ float b1s[32];
  __shared__ float b2s[16];
  int t = threadIdx.x;
  int base = blockIdx.x*64;
  for (int i=t; i<64*128; i+=256){
    int r=i>>7, c=i&127;
    xs[r*129+c] = (base+r<n) ? x[(size_t)(base+r)*128+c] : 0.f;
  }
  for (int i=t; i<128*32; i+=256) w1s[i]=Wm1[i];
  for (int i=t; i<32*16;  i+=256) w2s[i]=Wm2[i];
  if (t<32) b1s[t]=bm1[t];
  if (t<16) b2s[t]=bm2[t];
  __syncthreads();
  int l = t&63, g = t>>6;
  float hid[8];
  #pragma unroll
  for (int j=0;j<8;++j) hid[j]=0.f;
  for (int k=0;k<128;++k){
    float xk = xs[l*129+k];
    #pragma unroll
    for (int j=0;j<8;++j) hid[j] = fmaf(xk, w1s[k*32 + g*8 + j], hid[j]);
  }
  #pragma unroll
  for (int j=0;j<8;++j) hs[l*33 + g*8 + j] = fmaxf(hid[j] + b1s[g*8+j], 0.f);
  __syncthreads();
  float o[4] = {0.f,0.f,0.f,0.f};
  for (int k=0;k<32;++k){
    float xv = hs[l*33+k];
    #pragma unroll
    for (int j=0;j<4;++j) o[j] = fmaf(xv, w2s[k*16 + g*4 + j], o[j]);
  }
  int node = base + l;
  if (node < n){
    #pragma unroll
    for (int j=0;j<4;++j) out[(size_t)node*16 + g*4 + j] = o[j] + b2s[g*4+j];
  }
}

extern "C" void kernel_launch(void* const* d_in, const int* in_sizes, int n_in,
                              void* d_out, int out_size, void* d_ws, size_t ws_size,
                              hipStream_t stream)
{
  const float* x   = (const float*)d_in[0];
  const int*   ei  = (const int*)  d_in[1];
  const float* W0  = (const float*)d_in[2];
  const float* as0 = (const float*)d_in[3];
  const float* ad0 = (const float*)d_in[4];
  const float* b0  = (const float*)d_in[5];
  const float* W1  = (const float*)d_in[6];
  const float* as1 = (const float*)d_in[7];
  const float* ad1 = (const float*)d_in[8];
  const float* b1  = (const float*)d_in[9];
  const float* Wm1 = (const float*)d_in[10];
  const float* bm1 = (const float*)d_in[11];
  const float* Wm2 = (const float*)d_in[12];
  const float* bm2 = (const float*)d_in[13];
  int N = in_sizes[0]/128;
  int E = in_sizes[1]/2;
  const int* srcI = ei;
  const int* dstI = ei + E;

  char* ws = (char*)d_ws;
  size_t off = 0;
  auto alloc = [&](size_t bytes)->void*{
    void* p = ws + off; off += (bytes + 255) & ~(size_t)255; return p;
  };
  float* hbuf  = (float*)alloc((size_t)N*128*4);
  float* xbuf  = (float*)alloc((size_t)N*128*4);
  float* asb   = (float*)alloc((size_t)N*4*4);
  float* adb   = (float*)alloc((size_t)N*4*4);
  int* rowptr  = (int*)alloc((size_t)(N+1)*4);
  int* cnt     = (int*)alloc((size_t)N*4);
  int* fill    = (int*)alloc((size_t)N*4);
  int* bsum    = (int*)alloc(4096);
  int* boff    = (int*)alloc(4096);
  int* csr     = (int*)alloc((size_t)E*4);
  (void)ws_size; (void)n_in; (void)out_size;

  int B = (N+1023)/1024;
  hipMemsetAsync(cnt,  0, (size_t)N*4, stream);
  hipMemsetAsync(fill, 0, (size_t)N*4, stream);
  int gE = (E+255)/256;
  k_hist   <<<gE,256,0,stream>>>(dstI, cnt, E);
  k_scanA  <<<B, 256,0,stream>>>(cnt, rowptr, bsum, N);
  k_scanB  <<<1, 64, 0,stream>>>(bsum, boff, rowptr, B, N);
  k_scanC  <<<(N+255)/256,256,0,stream>>>(rowptr, boff, N);
  k_scatter<<<gE,256,0,stream>>>(srcI, dstI, rowptr, fill, csr, E);

  int gG = (N+63)/64;
  int gA = (int)(((size_t)N*64 + 255)/256);
  k_gemm_att<<<gG,256,0,stream>>>(x,    W0, as0, ad0, hbuf, asb, adb, N);
  k_aggr    <<<gA,256,0,stream>>>(hbuf, asb, adb, rowptr, csr, b0, xbuf, N);
  k_gemm_att<<<gG,256,0,stream>>>(xbuf, W1, as1, ad1, hbuf, asb, adb, N);
  k_aggr    <<<gA,256,0,stream>>>(hbuf, asb, adb, rowptr, csr, b1, xbuf, N);
  k_mlp     <<<gG,256,0,stream>>>(xbuf, Wm1, bm1, Wm2, bm2, (float*)d_out, N);
}

// Round 3
// 646.904 us; speedup vs baseline: 1.1568x; 1.0118x over previous
//
#include <hip/hip_runtime.h>
#include <hip/hip_bf16.h>

#define NEG 0.2f

// ---------------- CSR build ----------------
__global__ void k_hist(const int* __restrict__ dst, int* __restrict__ cnt, int E){
  int i = blockIdx.x*blockDim.x + threadIdx.x;
  if (i < E) atomicAdd(&cnt[dst[i]], 1);
}

__global__ void k_scanA(const int* __restrict__ cnt, int* __restrict__ exout,
                        int* __restrict__ bsum, int n){
  __shared__ int sd[256];
  int t = threadIdx.x, b = blockIdx.x;
  int base = b*1024 + t*4;
  int v0 = (base+0<n) ? cnt[base+0] : 0;
  int v1 = (base+1<n) ? cnt[base+1] : 0;
  int v2 = (base+2<n) ? cnt[base+2] : 0;
  int v3 = (base+3<n) ? cnt[base+3] : 0;
  int s = v0+v1+v2+v3;
  sd[t] = s; __syncthreads();
  for (int off=1; off<256; off<<=1){
    int x = (t>=off) ? sd[t-off] : 0;
    __syncthreads();
    sd[t] += x;
    __syncthreads();
  }
  int ex = sd[t] - s;
  if (t==255) bsum[b] = sd[t];
  if (base+0<n) exout[base+0]=ex; ex+=v0;
  if (base+1<n) exout[base+1]=ex; ex+=v1;
  if (base+2<n) exout[base+2]=ex; ex+=v2;
  if (base+3<n) exout[base+3]=ex;
}

__global__ void k_scanB(const int* __restrict__ bsum, int* __restrict__ boff,
                        int* __restrict__ rowptr, int B, int n){
  if (threadIdx.x==0){
    int run=0;
    for (int b=0;b<B;++b){ int t=bsum[b]; boff[b]=run; run+=t; }
    rowptr[n]=run;
  }
}

__global__ void k_scanC(int* __restrict__ rowptr, const int* __restrict__ boff, int n){
  int i = blockIdx.x*blockDim.x + threadIdx.x;
  if (i<n) rowptr[i] += boff[i>>10];
}

__global__ void k_scatter(const int* __restrict__ src, const int* __restrict__ dst,
                          const int* __restrict__ rowptr, int* __restrict__ fill,
                          int* __restrict__ csr, int E){
  int i = blockIdx.x*blockDim.x + threadIdx.x;
  if (i<E){
    int d = dst[i];
    int p = atomicAdd(&fill[d], 1);
    csr[rowptr[d]+p] = src[i];
  }
}

// ---------------- GEMM (x@W) fused with attention dots ----------------
__global__ __launch_bounds__(256) void k_gemm_att(
    const float* __restrict__ xin, const float* __restrict__ W,
    const float* __restrict__ atts, const float* __restrict__ attd,
    float* __restrict__ h, float* __restrict__ as_, float* __restrict__ ad_, int n)
{
  __shared__ float xs[64*129];
  int t = threadIdx.x;
  int base = blockIdx.x*64;
  for (int i=t; i<64*128; i+=256){
    int r = i>>7, c = i&127;
    xs[r*129+c] = (base+r < n) ? xin[(size_t)(base+r)*128 + c] : 0.f;
  }
  __syncthreads();
  int cx = t & 15, rn = t >> 4;
  int c0 = cx*8;
  int r0 = rn*4;
  float acc[4][8];
  #pragma unroll
  for (int r=0;r<4;++r)
    #pragma unroll
    for (int j=0;j<8;++j) acc[r][j]=0.f;
  const float4* W4 = reinterpret_cast<const float4*>(W);
  for (int k=0;k<128;++k){
    float4 wa = W4[(k*128 + c0)>>2];
    float4 wb = W4[(k*128 + c0 + 4)>>2];
    float w[8] = {wa.x,wa.y,wa.z,wa.w,wb.x,wb.y,wb.z,wb.w};
    #pragma unroll
    for (int r=0;r<4;++r){
      float xk = xs[(r0+r)*129 + k];
      #pragma unroll
      for (int j=0;j<8;++j) acc[r][j] = fmaf(xk, w[j], acc[r][j]);
    }
  }
  int head = cx>>2, q = cx&3;
  #pragma unroll
  for (int r=0;r<4;++r){
    int node = base + r0 + r;
    float ps=0.f, pd=0.f;
    #pragma unroll
    for (int j=0;j<8;++j){
      float av = atts[head*32 + q*8 + j];
      float dv = attd[head*32 + q*8 + j];
      ps = fmaf(acc[r][j], av, ps);
      pd = fmaf(acc[r][j], dv, pd);
    }
    ps += __shfl_xor(ps,1); ps += __shfl_xor(ps,2);
    pd += __shfl_xor(pd,1); pd += __shfl_xor(pd,2);
    if (node < n){
      float4 ha = make_float4(acc[r][0],acc[r][1],acc[r][2],acc[r][3]);
      float4 hb = make_float4(acc[r][4],acc[r][5],acc[r][6],acc[r][7]);
      float4* H4 = reinterpret_cast<float4*>(h + (size_t)node*128 + c0);
      H4[0]=ha; H4[1]=hb;
      if (q==0){ as_[node*4+head]=ps; ad_[node*4+head]=pd; }
    }
  }
}

// ---------------- per-node softmax-aggregation ----------------
// R3: 1 wave = 1 node, but the wave's two 32-lane halves process different
// edges concurrently; each lane owns 4 channels (float4 = 16B gathers).
// 8 edge rows in flight per wave; cross-half shfl reduce at the end.
__global__ __launch_bounds__(256) void k_aggr(
    const float* __restrict__ h, const float* __restrict__ as_,
    const float* __restrict__ ad_, const int* __restrict__ rowptr,
    const int* __restrict__ csr, const float* __restrict__ bias,
    float* __restrict__ out, int n)
{
  int wid = (int)((blockIdx.x*(size_t)blockDim.x + threadIdx.x) >> 6);
  int lane = threadIdx.x & 63;
  if (wid >= n) return;
  int half = lane >> 5;
  int li   = lane & 31;
  int c0   = li*4;
  int head = li >> 3;
  float adn = ad_[wid*4 + head];
  int beg = rowptr[wid], end = rowptr[wid+1];
  int deg = end - beg;
  float4 acc = make_float4(0.f,0.f,0.f,0.f);
  float z = 0.f;
  int nfull = deg & ~7;
  int lim = beg + nfull;
  for (int i = beg + half*4; i < lim; i += 8){
    int s0 = csr[i+0];
    int s1 = csr[i+1];
    int s2 = csr[i+2];
    int s3 = csr[i+3];
    float e0 = as_[s0*4+head];
    float e1 = as_[s1*4+head];
    float e2 = as_[s2*4+head];
    float e3 = as_[s3*4+head];
    float4 h0 = *reinterpret_cast<const float4*>(h + (size_t)s0*128 + c0);
    float4 h1 = *reinterpret_cast<const float4*>(h + (size_t)s1*128 + c0);
    float4 h2 = *reinterpret_cast<const float4*>(h + (size_t)s2*128 + c0);
    float4 h3 = *reinterpret_cast<const float4*>(h + (size_t)s3*128 + c0);
    e0 += adn; e1 += adn; e2 += adn; e3 += adn;
    e0 = (e0>0.f)?e0:NEG*e0;
    e1 = (e1>0.f)?e1:NEG*e1;
    e2 = (e2>0.f)?e2:NEG*e2;
    e3 = (e3>0.f)?e3:NEG*e3;
    float x0 = __expf(e0);
    float x1 = __expf(e1);
    float x2 = __expf(e2);
    float x3 = __expf(e3);
    z += (x0+x1)+(x2+x3);
    acc.x = fmaf(x0,h0.x,acc.x); acc.y = fmaf(x0,h0.y,acc.y);
    acc.z = fmaf(x0,h0.z,acc.z); acc.w = fmaf(x0,h0.w,acc.w);
    acc.x = fmaf(x1,h1.x,acc.x); acc.y = fmaf(x1,h1.y,acc.y);
    acc.z = fmaf(x1,h1.z,acc.z); acc.w = fmaf(x1,h1.w,acc.w);
    acc.x = fmaf(x2,h2.x,acc.x); acc.y = fmaf(x2,h2.y,acc.y);
    acc.z = fmaf(x2,h2.z,acc.z); acc.w = fmaf(x2,h2.w,acc.w);
    acc.x = fmaf(x3,h3.x,acc.x); acc.y = fmaf(x3,h3.y,acc.y);
    acc.z = fmaf(x3,h3.z,acc.z); acc.w = fmaf(x3,h3.w,acc.w);
  }
  for (int i = beg + nfull + half; i < end; i += 2){
    int s = csr[i];
    float e = as_[s*4+head] + adn;
    e = (e>0.f)?e:NEG*e;
    float ee = __expf(e);
    z += ee;
    float4 hv = *reinterpret_cast<const float4*>(h + (size_t)s*128 + c0);
    acc.x = fmaf(ee,hv.x,acc.x); acc.y = fmaf(ee,hv.y,acc.y);
    acc.z = fmaf(ee,hv.z,acc.z); acc.w = fmaf(ee,hv.w,acc.w);
  }
  z     += __shfl_xor(z, 32);
  acc.x += __shfl_xor(acc.x, 32);
  acc.y += __shfl_xor(acc.y, 32);
  acc.z += __shfl_xor(acc.z, 32);
  acc.w += __shfl_xor(acc.w, 32);
  if (half == 0){
    float4 o;
    if (deg > 0){
      float rz = 1.f/z;
      o.x = fmaxf(fmaf(acc.x,rz,bias[c0  ]), 0.f);
      o.y = fmaxf(fmaf(acc.y,rz,bias[c0+1]), 0.f);
      o.z = fmaxf(fmaf(acc.z,rz,bias[c0+2]), 0.f);
      o.w = fmaxf(fmaf(acc.w,rz,bias[c0+3]), 0.f);
    } else {
      o.x = fmaxf(bias[c0  ], 0.f);
      o.y = fmaxf(bias[c0+1], 0.f);
      o.z = fmaxf(bias[c0+2], 0.f);
      o.w = fmaxf(bias[c0+3], 0.f);
    }
    *reinterpret_cast<float4*>(out + (size_t)wid*128 + c0) = o;
  }
}

// ---------------- fused 2-layer MLP ----------------
__global__ __launch_bounds__(256) void k_mlp(
    const float* __restrict__ x, const float* __restrict__ Wm1, const float* __restrict__ bm1,
    const float* __restrict__ Wm2, const float* __restrict__ bm2,
    float* __restrict__ out, int n)
{
  __shared__ float xs[64*129];
  __shared__ float w1s[128*32];
  __shared__ float hs[64*33];
  __shared__ float w2s[32*16];
  __shared__ float b1s[32];
  __shared__ float b2s[16];
  int t = threadIdx.x;
  int base = blockIdx.x*64;
  for (int i=t; i<64*128; i+=256){
    int r=i>>7, c=i&127;
    xs[r*129+c] = (base+r<n) ? x[(size_t)(base+r)*128+c] : 0.f;
  }
  for (int i=t; i<128*32; i+=256) w1s[i]=Wm1[i];
  for (int i=t; i<32*16;  i+=256) w2s[i]=Wm2[i];
  if (t<32) b1s[t]=bm1[t];
  if (t<16) b2s[t]=bm2[t];
  __syncthreads();
  int l = t&63, g = t>>6;
  float hid[8];
  #pragma unroll
  for (int j=0;j<8;++j) hid[j]=0.f;
  for (int k=0;k<128;++k){
    float xk = xs[l*129+k];
    #pragma unroll
    for (int j=0;j<8;++j) hid[j] = fmaf(xk, w1s[k*32 + g*8 + j], hid[j]);
  }
  #pragma unroll
  for (int j=0;j<8;++j) hs[l*33 + g*8 + j] = fmaxf(hid[j] + b1s[g*8+j], 0.f);
  __syncthreads();
  float o[4] = {0.f,0.f,0.f,0.f};
  for (int k=0;k<32;++k){
    float xv = hs[l*33+k];
    #pragma unroll
    for (int j=0;j<4;++j) o[j] = fmaf(xv, w2s[k*16 + g*4 + j], o[j]);
  }
  int node = base + l;
  if (node < n){
    #pragma unroll
    for (int j=0;j<4;++j) out[(size_t)node*16 + g*4 + j] = o[j] + b2s[g*4+j];
  }
}

extern "C" void kernel_launch(void* const* d_in, const int* in_sizes, int n_in,
                              void* d_out, int out_size, void* d_ws, size_t ws_size,
                              hipStream_t stream)
{
  const float* x   = (const float*)d_in[0];
  const int*   ei  = (const int*)  d_in[1];
  const float* W0  = (const float*)d_in[2];
  const float* as0 = (const float*)d_in[3];
  const float* ad0 = (const float*)d_in[4];
  const float* b0  = (const float*)d_in[5];
  const float* W1  = (const float*)d_in[6];
  const float* as1 = (const float*)d_in[7];
  const float* ad1 = (const float*)d_in[8];
  const float* b1  = (const float*)d_in[9];
  const float* Wm1 = (const float*)d_in[10];
  const float* bm1 = (const float*)d_in[11];
  const float* Wm2 = (const float*)d_in[12];
  const float* bm2 = (const float*)d_in[13];
  int N = in_sizes[0]/128;
  int E = in_sizes[1]/2;
  const int* srcI = ei;
  const int* dstI = ei + E;

  char* ws = (char*)d_ws;
  size_t off = 0;
  auto alloc = [&](size_t bytes)->void*{
    void* p = ws + off; off += (bytes + 255) & ~(size_t)255; return p;
  };
  float* hbuf  = (float*)alloc((size_t)N*128*4);
  float* xbuf  = (float*)alloc((size_t)N*128*4);
  float* asb   = (float*)alloc((size_t)N*4*4);
  float* adb   = (float*)alloc((size_t)N*4*4);
  int* rowptr  = (int*)alloc((size_t)(N+1)*4);
  int* cnt     = (int*)alloc((size_t)N*4);
  int* fill    = (int*)alloc((size_t)N*4);
  int* bsum    = (int*)alloc(4096);
  int* boff    = (int*)alloc(4096);
  int* csr     = (int*)alloc((size_t)E*4);
  (void)ws_size; (void)n_in; (void)out_size;

  int B = (N+1023)/1024;
  hipMemsetAsync(cnt,  0, (size_t)N*4, stream);
  hipMemsetAsync(fill, 0, (size_t)N*4, stream);
  int gE = (E+255)/256;
  k_hist   <<<gE,256,0,stream>>>(dstI, cnt, E);
  k_scanA  <<<B, 256,0,stream>>>(cnt, rowptr, bsum, N);
  k_scanB  <<<1, 64, 0,stream>>>(bsum, boff, rowptr, B, N);
  k_scanC  <<<(N+255)/256,256,0,stream>>>(rowptr, boff, N);
  k_scatter<<<gE,256,0,stream>>>(srcI, dstI, rowptr, fill, csr, E);

  int gG = (N+63)/64;
  int gA = (int)(((size_t)N*64 + 255)/256);
  k_gemm_att<<<gG,256,0,stream>>>(x,    W0, as0, ad0, hbuf, asb, adb, N);
  k_aggr    <<<gA,256,0,stream>>>(hbuf, asb, adb, rowptr, csr, b0, xbuf, N);
  k_gemm_att<<<gG,256,0,stream>>>(xbuf, W1, as1, ad1, hbuf, asb, adb, N);
  k_aggr    <<<gA,256,0,stream>>>(hbuf, asb, adb, rowptr, csr, b1, xbuf, N);
  k_mlp     <<<gG,256,0,stream>>>(xbuf, Wm1, bm1, Wm2, bm2, (float*)d_out, N);
}

// Round 4
// 541.837 us; speedup vs baseline: 1.3811x; 1.1939x over previous
//
#include <hip/hip_runtime.h>
#include <hip/hip_bf16.h>

#define NEG 0.2f

static __device__ __forceinline__ float bf2f(unsigned int u16){
  return __uint_as_float(u16 << 16);
}
static __device__ __forceinline__ unsigned short f2bf(float f){
  __hip_bfloat16 h = __float2bfloat16(f);
  return *reinterpret_cast<unsigned short*>(&h);
}

// ---------------- CSR build ----------------
__global__ void k_hist(const int* __restrict__ dst, int* __restrict__ cnt, int E){
  int i = blockIdx.x*blockDim.x + threadIdx.x;
  if (i < E) atomicAdd(&cnt[dst[i]], 1);
}

__global__ void k_scanA(const int* __restrict__ cnt, int* __restrict__ exout,
                        int* __restrict__ bsum, int n){
  __shared__ int sd[256];
  int t = threadIdx.x, b = blockIdx.x;
  int base = b*1024 + t*4;
  int v0 = (base+0<n) ? cnt[base+0] : 0;
  int v1 = (base+1<n) ? cnt[base+1] : 0;
  int v2 = (base+2<n) ? cnt[base+2] : 0;
  int v3 = (base+3<n) ? cnt[base+3] : 0;
  int s = v0+v1+v2+v3;
  sd[t] = s; __syncthreads();
  for (int off=1; off<256; off<<=1){
    int x = (t>=off) ? sd[t-off] : 0;
    __syncthreads();
    sd[t] += x;
    __syncthreads();
  }
  int ex = sd[t] - s;
  if (t==255) bsum[b] = sd[t];
  if (base+0<n) exout[base+0]=ex; ex+=v0;
  if (base+1<n) exout[base+1]=ex; ex+=v1;
  if (base+2<n) exout[base+2]=ex; ex+=v2;
  if (base+3<n) exout[base+3]=ex;
}

__global__ void k_scanB(const int* __restrict__ bsum, int* __restrict__ boff,
                        int* __restrict__ rowptr, int B, int n){
  if (threadIdx.x==0){
    int run=0;
    for (int b=0;b<B;++b){ int t=bsum[b]; boff[b]=run; run+=t; }
    rowptr[n]=run;
  }
}

__global__ void k_scanC(int* __restrict__ rowptr, const int* __restrict__ boff, int n){
  int i = blockIdx.x*blockDim.x + threadIdx.x;
  if (i<n) rowptr[i] += boff[i>>10];
}

__global__ void k_scatter(const int* __restrict__ src, const int* __restrict__ dst,
                          const int* __restrict__ rowptr, int* __restrict__ fill,
                          int* __restrict__ csr, int E){
  int i = blockIdx.x*blockDim.x + threadIdx.x;
  if (i<E){
    int d = dst[i];
    int p = atomicAdd(&fill[d], 1);
    csr[rowptr[d]+p] = src[i];
  }
}

// ---------------- GEMM (x@W) fused with attention dots; h stored bf16 ------
__global__ __launch_bounds__(256) void k_gemm_att(
    const float* __restrict__ xin, const float* __restrict__ W,
    const float* __restrict__ atts, const float* __restrict__ attd,
    unsigned short* __restrict__ hb, float* __restrict__ as_, float* __restrict__ ad_, int n)
{
  __shared__ float xs[64*129];
  int t = threadIdx.x;
  int base = blockIdx.x*64;
  for (int i=t; i<64*128; i+=256){
    int r = i>>7, c = i&127;
    xs[r*129+c] = (base+r < n) ? xin[(size_t)(base+r)*128 + c] : 0.f;
  }
  __syncthreads();
  int cx = t & 15, rn = t >> 4;
  int c0 = cx*8;
  int r0 = rn*4;
  float acc[4][8];
  #pragma unroll
  for (int r=0;r<4;++r)
    #pragma unroll
    for (int j=0;j<8;++j) acc[r][j]=0.f;
  const float4* W4 = reinterpret_cast<const float4*>(W);
  for (int k=0;k<128;++k){
    float4 wa = W4[(k*128 + c0)>>2];
    float4 wb = W4[(k*128 + c0 + 4)>>2];
    float w[8] = {wa.x,wa.y,wa.z,wa.w,wb.x,wb.y,wb.z,wb.w};
    #pragma unroll
    for (int r=0;r<4;++r){
      float xk = xs[(r0+r)*129 + k];
      #pragma unroll
      for (int j=0;j<8;++j) acc[r][j] = fmaf(xk, w[j], acc[r][j]);
    }
  }
  int head = cx>>2, q = cx&3;
  #pragma unroll
  for (int r=0;r<4;++r){
    int node = base + r0 + r;
    float ps=0.f, pd=0.f;
    #pragma unroll
    for (int j=0;j<8;++j){
      float av = atts[head*32 + q*8 + j];
      float dv = attd[head*32 + q*8 + j];
      ps = fmaf(acc[r][j], av, ps);
      pd = fmaf(acc[r][j], dv, pd);
    }
    ps += __shfl_xor(ps,1); ps += __shfl_xor(ps,2);
    pd += __shfl_xor(pd,1); pd += __shfl_xor(pd,2);
    if (node < n){
      uint4 pk;
      pk.x = (unsigned int)f2bf(acc[r][0]) | ((unsigned int)f2bf(acc[r][1])<<16);
      pk.y = (unsigned int)f2bf(acc[r][2]) | ((unsigned int)f2bf(acc[r][3])<<16);
      pk.z = (unsigned int)f2bf(acc[r][4]) | ((unsigned int)f2bf(acc[r][5])<<16);
      pk.w = (unsigned int)f2bf(acc[r][6]) | ((unsigned int)f2bf(acc[r][7])<<16);
      *reinterpret_cast<uint4*>(hb + (size_t)node*128 + c0) = pk;
      if (q==0){ as_[node*4+head]=ps; ad_[node*4+head]=pd; }
    }
  }
}

// ---------------- per-node softmax-aggregation ----------------
// 1 wave = 1 node; two 32-lane halves process different edges; each lane owns
// 4 channels loaded as uint2 of packed bf16 (8B/lane -> 256B/row/half).
__global__ __launch_bounds__(256) void k_aggr(
    const unsigned short* __restrict__ hb, const float* __restrict__ as_,
    const float* __restrict__ ad_, const int* __restrict__ rowptr,
    const int* __restrict__ csr, const float* __restrict__ bias,
    float* __restrict__ out, int n)
{
  int wid = (int)((blockIdx.x*(size_t)blockDim.x + threadIdx.x) >> 6);
  int lane = threadIdx.x & 63;
  if (wid >= n) return;
  int half = lane >> 5;
  int li   = lane & 31;
  int c0   = li*4;
  int head = li >> 3;
  float adn = ad_[wid*4 + head];
  int beg = rowptr[wid], end = rowptr[wid+1];
  int deg = end - beg;
  float4 acc = make_float4(0.f,0.f,0.f,0.f);
  float z = 0.f;
  int nfull = deg & ~7;
  int lim = beg + nfull;
  int i = beg + half*4;
  int s0=0,s1=0,s2=0,s3=0;
  if (i < lim){ s0=csr[i]; s1=csr[i+1]; s2=csr[i+2]; s3=csr[i+3]; }
  for (; i < lim; ){
    int ni = i + 8;
    int t0=0,t1=0,t2=0,t3=0;
    if (ni < lim){ t0=csr[ni]; t1=csr[ni+1]; t2=csr[ni+2]; t3=csr[ni+3]; }
    float e0 = as_[s0*4+head];
    float e1 = as_[s1*4+head];
    float e2 = as_[s2*4+head];
    float e3 = as_[s3*4+head];
    uint2 p0 = *reinterpret_cast<const uint2*>(hb + (size_t)s0*128 + c0);
    uint2 p1 = *reinterpret_cast<const uint2*>(hb + (size_t)s1*128 + c0);
    uint2 p2 = *reinterpret_cast<const uint2*>(hb + (size_t)s2*128 + c0);
    uint2 p3 = *reinterpret_cast<const uint2*>(hb + (size_t)s3*128 + c0);
    e0 += adn; e1 += adn; e2 += adn; e3 += adn;
    e0 = (e0>0.f)?e0:NEG*e0;
    e1 = (e1>0.f)?e1:NEG*e1;
    e2 = (e2>0.f)?e2:NEG*e2;
    e3 = (e3>0.f)?e3:NEG*e3;
    float x0 = __expf(e0);
    float x1 = __expf(e1);
    float x2 = __expf(e2);
    float x3 = __expf(e3);
    z += (x0+x1)+(x2+x3);
    acc.x = fmaf(x0, bf2f(p0.x & 0xffffu), acc.x);
    acc.y = fmaf(x0, bf2f(p0.x >> 16),     acc.y);
    acc.z = fmaf(x0, bf2f(p0.y & 0xffffu), acc.z);
    acc.w = fmaf(x0, bf2f(p0.y >> 16),     acc.w);
    acc.x = fmaf(x1, bf2f(p1.x & 0xffffu), acc.x);
    acc.y = fmaf(x1, bf2f(p1.x >> 16),     acc.y);
    acc.z = fmaf(x1, bf2f(p1.y & 0xffffu), acc.z);
    acc.w = fmaf(x1, bf2f(p1.y >> 16),     acc.w);
    acc.x = fmaf(x2, bf2f(p2.x & 0xffffu), acc.x);
    acc.y = fmaf(x2, bf2f(p2.x >> 16),     acc.y);
    acc.z = fmaf(x2, bf2f(p2.y & 0xffffu), acc.z);
    acc.w = fmaf(x2, bf2f(p2.y >> 16),     acc.w);
    acc.x = fmaf(x3, bf2f(p3.x & 0xffffu), acc.x);
    acc.y = fmaf(x3, bf2f(p3.x >> 16),     acc.y);
    acc.z = fmaf(x3, bf2f(p3.y & 0xffffu), acc.z);
    acc.w = fmaf(x3, bf2f(p3.y >> 16),     acc.w);
    i = ni; s0=t0; s1=t1; s2=t2; s3=t3;
  }
  for (int j = beg + nfull + half; j < end; j += 2){
    int s = csr[j];
    float e = as_[s*4+head] + adn;
    e = (e>0.f)?e:NEG*e;
    float ee = __expf(e);
    z += ee;
    uint2 pv = *reinterpret_cast<const uint2*>(hb + (size_t)s*128 + c0);
    acc.x = fmaf(ee, bf2f(pv.x & 0xffffu), acc.x);
    acc.y = fmaf(ee, bf2f(pv.x >> 16),     acc.y);
    acc.z = fmaf(ee, bf2f(pv.y & 0xffffu), acc.z);
    acc.w = fmaf(ee, bf2f(pv.y >> 16),     acc.w);
  }
  z     += __shfl_xor(z, 32);
  acc.x += __shfl_xor(acc.x, 32);
  acc.y += __shfl_xor(acc.y, 32);
  acc.z += __shfl_xor(acc.z, 32);
  acc.w += __shfl_xor(acc.w, 32);
  if (half == 0){
    float4 o;
    if (deg > 0){
      float rz = 1.f/z;
      o.x = fmaxf(fmaf(acc.x,rz,bias[c0  ]), 0.f);
      o.y = fmaxf(fmaf(acc.y,rz,bias[c0+1]), 0.f);
      o.z = fmaxf(fmaf(acc.z,rz,bias[c0+2]), 0.f);
      o.w = fmaxf(fmaf(acc.w,rz,bias[c0+3]), 0.f);
    } else {
      o.x = fmaxf(bias[c0  ], 0.f);
      o.y = fmaxf(bias[c0+1], 0.f);
      o.z = fmaxf(bias[c0+2], 0.f);
      o.w = fmaxf(bias[c0+3], 0.f);
    }
    *reinterpret_cast<float4*>(out + (size_t)wid*128 + c0) = o;
  }
}

// ---------------- fused 2-layer MLP ----------------
__global__ __launch_bounds__(256) void k_mlp(
    const float* __restrict__ x, const float* __restrict__ Wm1, const float* __restrict__ bm1,
    const float* __restrict__ Wm2, const float* __restrict__ bm2,
    float* __restrict__ out, int n)
{
  __shared__ float xs[64*129];
  __shared__ float w1s[128*32];
  __shared__ float hs[64*33];
  __shared__ float w2s[32*16];
  __shared__ float b1s[32];
  __shared__ float b2s[16];
  int t = threadIdx.x;
  int base = blockIdx.x*64;
  for (int i=t; i<64*128; i+=256){
    int r=i>>7, c=i&127;
    xs[r*129+c] = (base+r<n) ? x[(size_t)(base+r)*128+c] : 0.f;
  }
  for (int i=t; i<128*32; i+=256) w1s[i]=Wm1[i];
  for (int i=t; i<32*16;  i+=256) w2s[i]=Wm2[i];
  if (t<32) b1s[t]=bm1[t];
  if (t<16) b2s[t]=bm2[t];
  __syncthreads();
  int l = t&63, g = t>>6;
  float hid[8];
  #pragma unroll
  for (int j=0;j<8;++j) hid[j]=0.f;
  for (int k=0;k<128;++k){
    float xk = xs[l*129+k];
    #pragma unroll
    for (int j=0;j<8;++j) hid[j] = fmaf(xk, w1s[k*32 + g*8 + j], hid[j]);
  }
  #pragma unroll
  for (int j=0;j<8;++j) hs[l*33 + g*8 + j] = fmaxf(hid[j] + b1s[g*8+j], 0.f);
  __syncthreads();
  float o[4] = {0.f,0.f,0.f,0.f};
  for (int k=0;k<32;++k){
    float xv = hs[l*33+k];
    #pragma unroll
    for (int j=0;j<4;++j) o[j] = fmaf(xv, w2s[k*16 + g*4 + j], o[j]);
  }
  int node = base + l;
  if (node < n){
    #pragma unroll
    for (int j=0;j<4;++j) out[(size_t)node*16 + g*4 + j] = o[j] + b2s[g*4+j];
  }
}

extern "C" void kernel_launch(void* const* d_in, const int* in_sizes, int n_in,
                              void* d_out, int out_size, void* d_ws, size_t ws_size,
                              hipStream_t stream)
{
  const float* x   = (const float*)d_in[0];
  const int*   ei  = (const int*)  d_in[1];
  const float* W0  = (const float*)d_in[2];
  const float* as0 = (const float*)d_in[3];
  const float* ad0 = (const float*)d_in[4];
  const float* b0  = (const float*)d_in[5];
  const float* W1  = (const float*)d_in[6];
  const float* as1 = (const float*)d_in[7];
  const float* ad1 = (const float*)d_in[8];
  const float* b1  = (const float*)d_in[9];
  const float* Wm1 = (const float*)d_in[10];
  const float* bm1 = (const float*)d_in[11];
  const float* Wm2 = (const float*)d_in[12];
  const float* bm2 = (const float*)d_in[13];
  int N = in_sizes[0]/128;
  int E = in_sizes[1]/2;
  const int* srcI = ei;
  const int* dstI = ei + E;

  char* ws = (char*)d_ws;
  size_t off = 0;
  auto alloc = [&](size_t bytes)->void*{
    void* p = ws + off; off += (bytes + 255) & ~(size_t)255; return p;
  };
  unsigned short* hbuf = (unsigned short*)alloc((size_t)N*128*2);
  float* xbuf  = (float*)alloc((size_t)N*128*4);
  float* asb   = (float*)alloc((size_t)N*4*4);
  float* adb   = (float*)alloc((size_t)N*4*4);
  int* rowptr  = (int*)alloc((size_t)(N+1)*4);
  int* cnt     = (int*)alloc((size_t)N*4);
  int* fill    = (int*)alloc((size_t)N*4);
  int* bsum    = (int*)alloc(4096);
  int* boff    = (int*)alloc(4096);
  int* csr     = (int*)alloc((size_t)E*4);
  (void)ws_size; (void)n_in; (void)out_size;

  int B = (N+1023)/1024;
  hipMemsetAsync(cnt,  0, (size_t)N*4, stream);
  hipMemsetAsync(fill, 0, (size_t)N*4, stream);
  int gE = (E+255)/256;
  k_hist   <<<gE,256,0,stream>>>(dstI, cnt, E);
  k_scanA  <<<B, 256,0,stream>>>(cnt, rowptr, bsum, N);
  k_scanB  <<<1, 64, 0,stream>>>(bsum, boff, rowptr, B, N);
  k_scanC  <<<(N+255)/256,256,0,stream>>>(rowptr, boff, N);
  k_scatter<<<gE,256,0,stream>>>(srcI, dstI, rowptr, fill, csr, E);

  int gG = (N+63)/64;
  int gA = (int)(((size_t)N*64 + 255)/256);
  k_gemm_att<<<gG,256,0,stream>>>(x,    W0, as0, ad0, hbuf, asb, adb, N);
  k_aggr    <<<gA,256,0,stream>>>(hbuf, asb, adb, rowptr, csr, b0, xbuf, N);
  k_gemm_att<<<gG,256,0,stream>>>(xbuf, W1, as1, ad1, hbuf, asb, adb, N);
  k_aggr    <<<gA,256,0,stream>>>(hbuf, asb, adb, rowptr, csr, b1, xbuf, N);
  k_mlp     <<<gG,256,0,stream>>>(xbuf, Wm1, bm1, Wm2, bm2, (float*)d_out, N);
}

// Round 5
// 481.894 us; speedup vs baseline: 1.5529x; 1.1244x over previous
//
#include <hip/hip_runtime.h>
#include <hip/hip_bf16.h>

#define NEG 0.2f

static __device__ __forceinline__ float bf2f(unsigned int u16){
  return __uint_as_float(u16 << 16);
}
static __device__ __forceinline__ unsigned short f2bf(float f){
  __hip_bfloat16 h = __float2bfloat16(f);
  return *reinterpret_cast<unsigned short*>(&h);
}

// ---------------- CSR build ----------------
__global__ void k_hist(const int* __restrict__ dst, int* __restrict__ cnt, int E){
  int i = blockIdx.x*blockDim.x + threadIdx.x;
  if (i < E) atomicAdd(&cnt[dst[i]], 1);
}

__global__ void k_scanA(const int* __restrict__ cnt, int* __restrict__ exout,
                        int* __restrict__ bsum, int n){
  __shared__ int sd[256];
  int t = threadIdx.x, b = blockIdx.x;
  int base = b*1024 + t*4;
  int v0 = (base+0<n) ? cnt[base+0] : 0;
  int v1 = (base+1<n) ? cnt[base+1] : 0;
  int v2 = (base+2<n) ? cnt[base+2] : 0;
  int v3 = (base+3<n) ? cnt[base+3] : 0;
  int s = v0+v1+v2+v3;
  sd[t] = s; __syncthreads();
  for (int off=1; off<256; off<<=1){
    int x = (t>=off) ? sd[t-off] : 0;
    __syncthreads();
    sd[t] += x;
    __syncthreads();
  }
  int ex = sd[t] - s;
  if (t==255) bsum[b] = sd[t];
  if (base+0<n) exout[base+0]=ex; ex+=v0;
  if (base+1<n) exout[base+1]=ex; ex+=v1;
  if (base+2<n) exout[base+2]=ex; ex+=v2;
  if (base+3<n) exout[base+3]=ex;
}

__global__ void k_scanB(const int* __restrict__ bsum, int* __restrict__ boff,
                        int* __restrict__ rowptr, int B, int n){
  if (threadIdx.x==0){
    int run=0;
    for (int b=0;b<B;++b){ int t=bsum[b]; boff[b]=run; run+=t; }
    rowptr[n]=run;
  }
}

__global__ void k_scanC(int* __restrict__ rowptr, const int* __restrict__ boff, int n){
  int i = blockIdx.x*blockDim.x + threadIdx.x;
  if (i<n) rowptr[i] += boff[i>>10];
}

// bucket b covers nodes [b*256, (b+1)*256); its csr range is
// [rowptr[b*256], rowptr[min((b+1)*256,N)]). bfill[b] = running fill ptr.
__global__ void k_binit(const int* __restrict__ rowptr, int* __restrict__ bfill,
                        int NB, int n){
  int b = blockIdx.x*blockDim.x + threadIdx.x;
  if (b < NB){
    int nb = b << 8; if (nb > n) nb = n;
    bfill[b] = rowptr[nb];
  }
}

// Pass 1: bin edges into bucket regions of pairs[] (packed: src<<8 | dst&255).
// Block-level LDS aggregation: LDS hist -> 1 global atomic per (block,bucket)
// -> LDS-atomic local placement.
#define CHUNK 2048
#define PER_T 8
__global__ __launch_bounds__(256) void k_binpass(
    const int* __restrict__ src, const int* __restrict__ dst,
    int* __restrict__ bfill, unsigned int* __restrict__ pairs, int E, int NB)
{
  __shared__ int lcnt[512];
  __shared__ int lbase[512];
  int t = threadIdx.x;
  int ebase = blockIdx.x * CHUNK;
  for (int j=t; j<NB; j+=256) lcnt[j]=0;
  __syncthreads();
  unsigned int pv[PER_T]; int pb[PER_T];
  #pragma unroll
  for (int k=0;k<PER_T;++k){
    int i = ebase + t + k*256;
    pb[k] = -1;
    if (i < E){
      int d = dst[i];
      int s = src[i];
      pb[k] = d >> 8;
      pv[k] = ((unsigned int)s << 8) | (unsigned int)(d & 255);
      atomicAdd(&lcnt[pb[k]], 1);
    }
  }
  __syncthreads();
  for (int j=t; j<NB; j+=256){
    int c = lcnt[j];
    lbase[j] = c ? atomicAdd(&bfill[j], c) : 0;
    lcnt[j] = 0;
  }
  __syncthreads();
  #pragma unroll
  for (int k=0;k<PER_T;++k){
    if (pb[k] >= 0){
      int ofs = atomicAdd(&lcnt[pb[k]], 1);
      pairs[lbase[pb[k]] + ofs] = pv[k];
    }
  }
}

// Pass 2: one block per bucket; redistribute within bucket. rowptr slice and
// fill counters in LDS; csr writes confined to the bucket's ~12KB region.
__global__ __launch_bounds__(256) void k_csr(
    const unsigned int* __restrict__ pairs, const int* __restrict__ rowptr,
    int* __restrict__ csr, int n)
{
  __shared__ int rp[257];
  __shared__ int fil[256];
  int b = blockIdx.x;
  int base = b << 8;
  int t = threadIdx.x;
  int cnt = n - base; if (cnt > 256) cnt = 256;
  for (int j=t; j<=cnt; j+=256) rp[j] = rowptr[base + j];
  if (t < cnt) fil[t] = 0;
  __syncthreads();
  int beg = rp[0], end = rp[cnt];
  for (int i = beg + t; i < end; i += 256){
    unsigned int p = pairs[i];
    int d = (int)(p & 255u);
    int ofs = atomicAdd(&fil[d], 1);
    csr[rp[d] + ofs] = (int)(p >> 8);
  }
}

// ---------------- GEMM (x@W) fused with attention dots; h stored bf16 ------
__global__ __launch_bounds__(256) void k_gemm_att(
    const float* __restrict__ xin, const float* __restrict__ W,
    const float* __restrict__ atts, const float* __restrict__ attd,
    unsigned short* __restrict__ hb, float* __restrict__ as_, float* __restrict__ ad_, int n)
{
  __shared__ float xs[64*129];
  int t = threadIdx.x;
  int base = blockIdx.x*64;
  for (int i=t; i<64*128; i+=256){
    int r = i>>7, c = i&127;
    xs[r*129+c] = (base+r < n) ? xin[(size_t)(base+r)*128 + c] : 0.f;
  }
  __syncthreads();
  int cx = t & 15, rn = t >> 4;
  int c0 = cx*8;
  int r0 = rn*4;
  float acc[4][8];
  #pragma unroll
  for (int r=0;r<4;++r)
    #pragma unroll
    for (int j=0;j<8;++j) acc[r][j]=0.f;
  const float4* W4 = reinterpret_cast<const float4*>(W);
  for (int k=0;k<128;++k){
    float4 wa = W4[(k*128 + c0)>>2];
    float4 wb = W4[(k*128 + c0 + 4)>>2];
    float w[8] = {wa.x,wa.y,wa.z,wa.w,wb.x,wb.y,wb.z,wb.w};
    #pragma unroll
    for (int r=0;r<4;++r){
      float xk = xs[(r0+r)*129 + k];
      #pragma unroll
      for (int j=0;j<8;++j) acc[r][j] = fmaf(xk, w[j], acc[r][j]);
    }
  }
  int head = cx>>2, q = cx&3;
  #pragma unroll
  for (int r=0;r<4;++r){
    int node = base + r0 + r;
    float ps=0.f, pd=0.f;
    #pragma unroll
    for (int j=0;j<8;++j){
      float av = atts[head*32 + q*8 + j];
      float dv = attd[head*32 + q*8 + j];
      ps = fmaf(acc[r][j], av, ps);
      pd = fmaf(acc[r][j], dv, pd);
    }
    ps += __shfl_xor(ps,1); ps += __shfl_xor(ps,2);
    pd += __shfl_xor(pd,1); pd += __shfl_xor(pd,2);
    if (node < n){
      uint4 pk;
      pk.x = (unsigned int)f2bf(acc[r][0]) | ((unsigned int)f2bf(acc[r][1])<<16);
      pk.y = (unsigned int)f2bf(acc[r][2]) | ((unsigned int)f2bf(acc[r][3])<<16);
      pk.z = (unsigned int)f2bf(acc[r][4]) | ((unsigned int)f2bf(acc[r][5])<<16);
      pk.w = (unsigned int)f2bf(acc[r][6]) | ((unsigned int)f2bf(acc[r][7])<<16);
      *reinterpret_cast<uint4*>(hb + (size_t)node*128 + c0) = pk;
      if (q==0){ as_[node*4+head]=ps; ad_[node*4+head]=pd; }
    }
  }
}

// ---------------- per-node softmax-aggregation ----------------
__global__ __launch_bounds__(256) void k_aggr(
    const unsigned short* __restrict__ hb, const float* __restrict__ as_,
    const float* __restrict__ ad_, const int* __restrict__ rowptr,
    const int* __restrict__ csr, const float* __restrict__ bias,
    float* __restrict__ out, int n)
{
  int wid = (int)((blockIdx.x*(size_t)blockDim.x + threadIdx.x) >> 6);
  int lane = threadIdx.x & 63;
  if (wid >= n) return;
  int half = lane >> 5;
  int li   = lane & 31;
  int c0   = li*4;
  int head = li >> 3;
  float adn = ad_[wid*4 + head];
  int beg = rowptr[wid], end = rowptr[wid+1];
  int deg = end - beg;
  float4 acc = make_float4(0.f,0.f,0.f,0.f);
  float z = 0.f;
  int nfull = deg & ~7;
  int lim = beg + nfull;
  int i = beg + half*4;
  int s0=0,s1=0,s2=0,s3=0;
  if (i < lim){ s0=csr[i]; s1=csr[i+1]; s2=csr[i+2]; s3=csr[i+3]; }
  for (; i < lim; ){
    int ni = i + 8;
    int t0=0,t1=0,t2=0,t3=0;
    if (ni < lim){ t0=csr[ni]; t1=csr[ni+1]; t2=csr[ni+2]; t3=csr[ni+3]; }
    float e0 = as_[s0*4+head];
    float e1 = as_[s1*4+head];
    float e2 = as_[s2*4+head];
    float e3 = as_[s3*4+head];
    uint2 p0 = *reinterpret_cast<const uint2*>(hb + (size_t)s0*128 + c0);
    uint2 p1 = *reinterpret_cast<const uint2*>(hb + (size_t)s1*128 + c0);
    uint2 p2 = *reinterpret_cast<const uint2*>(hb + (size_t)s2*128 + c0);
    uint2 p3 = *reinterpret_cast<const uint2*>(hb + (size_t)s3*128 + c0);
    e0 += adn; e1 += adn; e2 += adn; e3 += adn;
    e0 = (e0>0.f)?e0:NEG*e0;
    e1 = (e1>0.f)?e1:NEG*e1;
    e2 = (e2>0.f)?e2:NEG*e2;
    e3 = (e3>0.f)?e3:NEG*e3;
    float x0 = __expf(e0);
    float x1 = __expf(e1);
    float x2 = __expf(e2);
    float x3 = __expf(e3);
    z += (x0+x1)+(x2+x3);
    acc.x = fmaf(x0, bf2f(p0.x & 0xffffu), acc.x);
    acc.y = fmaf(x0, bf2f(p0.x >> 16),     acc.y);
    acc.z = fmaf(x0, bf2f(p0.y & 0xffffu), acc.z);
    acc.w = fmaf(x0, bf2f(p0.y >> 16),     acc.w);
    acc.x = fmaf(x1, bf2f(p1.x & 0xffffu), acc.x);
    acc.y = fmaf(x1, bf2f(p1.x >> 16),     acc.y);
    acc.z = fmaf(x1, bf2f(p1.y & 0xffffu), acc.z);
    acc.w = fmaf(x1, bf2f(p1.y >> 16),     acc.w);
    acc.x = fmaf(x2, bf2f(p2.x & 0xffffu), acc.x);
    acc.y = fmaf(x2, bf2f(p2.x >> 16),     acc.y);
    acc.z = fmaf(x2, bf2f(p2.y & 0xffffu), acc.z);
    acc.w = fmaf(x2, bf2f(p2.y >> 16),     acc.w);
    acc.x = fmaf(x3, bf2f(p3.x & 0xffffu), acc.x);
    acc.y = fmaf(x3, bf2f(p3.x >> 16),     acc.y);
    acc.z = fmaf(x3, bf2f(p3.y & 0xffffu), acc.z);
    acc.w = fmaf(x3, bf2f(p3.y >> 16),     acc.w);
    i = ni; s0=t0; s1=t1; s2=t2; s3=t3;
  }
  for (int j = beg + nfull + half; j < end; j += 2){
    int s = csr[j];
    float e = as_[s*4+head] + adn;
    e = (e>0.f)?e:NEG*e;
    float ee = __expf(e);
    z += ee;
    uint2 pv = *reinterpret_cast<const uint2*>(hb + (size_t)s*128 + c0);
    acc.x = fmaf(ee, bf2f(pv.x & 0xffffu), acc.x);
    acc.y = fmaf(ee, bf2f(pv.x >> 16),     acc.y);
    acc.z = fmaf(ee, bf2f(pv.y & 0xffffu), acc.z);
    acc.w = fmaf(ee, bf2f(pv.y >> 16),     acc.w);
  }
  z     += __shfl_xor(z, 32);
  acc.x += __shfl_xor(acc.x, 32);
  acc.y += __shfl_xor(acc.y, 32);
  acc.z += __shfl_xor(acc.z, 32);
  acc.w += __shfl_xor(acc.w, 32);
  if (half == 0){
    float4 o;
    if (deg > 0){
      float rz = 1.f/z;
      o.x = fmaxf(fmaf(acc.x,rz,bias[c0  ]), 0.f);
      o.y = fmaxf(fmaf(acc.y,rz,bias[c0+1]), 0.f);
      o.z = fmaxf(fmaf(acc.z,rz,bias[c0+2]), 0.f);
      o.w = fmaxf(fmaf(acc.w,rz,bias[c0+3]), 0.f);
    } else {
      o.x = fmaxf(bias[c0  ], 0.f);
      o.y = fmaxf(bias[c0+1], 0.f);
      o.z = fmaxf(bias[c0+2], 0.f);
      o.w = fmaxf(bias[c0+3], 0.f);
    }
    *reinterpret_cast<float4*>(out + (size_t)wid*128 + c0) = o;
  }
}

// ---------------- fused 2-layer MLP ----------------
__global__ __launch_bounds__(256) void k_mlp(
    const float* __restrict__ x, const float* __restrict__ Wm1, const float* __restrict__ bm1,
    const float* __restrict__ Wm2, const float* __restrict__ bm2,
    float* __restrict__ out, int n)
{
  __shared__ float xs[64*129];
  __shared__ float w1s[128*32];
  __shared__ float hs[64*33];
  __shared__ float w2s[32*16];
  __shared__ float b1s[32];
  __shared__ float b2s[16];
  int t = threadIdx.x;
  int base = blockIdx.x*64;
  for (int i=t; i<64*128; i+=256){
    int r=i>>7, c=i&127;
    xs[r*129+c] = (base+r<n) ? x[(size_t)(base+r)*128+c] : 0.f;
  }
  for (int i=t; i<128*32; i+=256) w1s[i]=Wm1[i];
  for (int i=t; i<32*16;  i+=256) w2s[i]=Wm2[i];
  if (t<32) b1s[t]=bm1[t];
  if (t<16) b2s[t]=bm2[t];
  __syncthreads();
  int l = t&63, g = t>>6;
  float hid[8];
  #pragma unroll
  for (int j=0;j<8;++j) hid[j]=0.f;
  for (int k=0;k<128;++k){
    float xk = xs[l*129+k];
    #pragma unroll
    for (int j=0;j<8;++j) hid[j] = fmaf(xk, w1s[k*32 + g*8 + j], hid[j]);
  }
  #pragma unroll
  for (int j=0;j<8;++j) hs[l*33 + g*8 + j] = fmaxf(hid[j] + b1s[g*8+j], 0.f);
  __syncthreads();
  float o[4] = {0.f,0.f,0.f,0.f};
  for (int k=0;k<32;++k){
    float xv = hs[l*33+k];
    #pragma unroll
    for (int j=0;j<4;++j) o[j] = fmaf(xv, w2s[k*16 + g*4 + j], o[j]);
  }
  int node = base + l;
  if (node < n){
    #pragma unroll
    for (int j=0;j<4;++j) out[(size_t)node*16 + g*4 + j] = o[j] + b2s[g*4+j];
  }
}

extern "C" void kernel_launch(void* const* d_in, const int* in_sizes, int n_in,
                              void* d_out, int out_size, void* d_ws, size_t ws_size,
                              hipStream_t stream)
{
  const float* x   = (const float*)d_in[0];
  const int*   ei  = (const int*)  d_in[1];
  const float* W0  = (const float*)d_in[2];
  const float* as0 = (const float*)d_in[3];
  const float* ad0 = (const float*)d_in[4];
  const float* b0  = (const float*)d_in[5];
  const float* W1  = (const float*)d_in[6];
  const float* as1 = (const float*)d_in[7];
  const float* ad1 = (const float*)d_in[8];
  const float* b1  = (const float*)d_in[9];
  const float* Wm1 = (const float*)d_in[10];
  const float* bm1 = (const float*)d_in[11];
  const float* Wm2 = (const float*)d_in[12];
  const float* bm2 = (const float*)d_in[13];
  int N = in_sizes[0]/128;
  int E = in_sizes[1]/2;
  const int* srcI = ei;
  const int* dstI = ei + E;

  char* ws = (char*)d_ws;
  size_t off = 0;
  auto alloc = [&](size_t bytes)->void*{
    void* p = ws + off; off += (bytes + 255) & ~(size_t)255; return p;
  };
  unsigned short* hbuf = (unsigned short*)alloc((size_t)N*128*2);
  float* xbuf  = (float*)alloc((size_t)N*128*4);
  float* asb   = (float*)alloc((size_t)N*4*4);
  float* adb   = (float*)alloc((size_t)N*4*4);
  int* rowptr  = (int*)alloc((size_t)(N+1)*4);
  int* cnt     = (int*)alloc((size_t)N*4);
  int* bfill   = (int*)alloc(4096);
  int* bsum    = (int*)alloc(4096);
  int* boff    = (int*)alloc(4096);
  int* csr     = (int*)alloc((size_t)E*4);
  unsigned int* pairs = (unsigned int*)alloc((size_t)E*4);
  (void)ws_size; (void)n_in; (void)out_size;

  int NB = (N + 255) >> 8;   // 256-node buckets (<=512 for LDS tables)
  int B = (N+1023)/1024;
  hipMemsetAsync(cnt, 0, (size_t)N*4, stream);
  int gE = (E+255)/256;
  k_hist   <<<gE,256,0,stream>>>(dstI, cnt, E);
  k_scanA  <<<B, 256,0,stream>>>(cnt, rowptr, bsum, N);
  k_scanB  <<<1, 64, 0,stream>>>(bsum, boff, rowptr, B, N);
  k_scanC  <<<(N+255)/256,256,0,stream>>>(rowptr, boff, N);
  k_binit  <<<(NB+255)/256,256,0,stream>>>(rowptr, bfill, NB, N);
  k_binpass<<<(E+CHUNK-1)/CHUNK,256,0,stream>>>(srcI, dstI, bfill, pairs, E, NB);
  k_csr    <<<NB,256,0,stream>>>(pairs, rowptr, csr, N);

  int gG = (N+63)/64;
  int gA = (int)(((size_t)N*64 + 255)/256);
  k_gemm_att<<<gG,256,0,stream>>>(x,    W0, as0, ad0, hbuf, asb, adb, N);
  k_aggr    <<<gA,256,0,stream>>>(hbuf, asb, adb, rowptr, csr, b0, xbuf, N);
  k_gemm_att<<<gG,256,0,stream>>>(xbuf, W1, as1, ad1, hbuf, asb, adb, N);
  k_aggr    <<<gA,256,0,stream>>>(hbuf, asb, adb, rowptr, csr, b1, xbuf, N);
  k_mlp     <<<gG,256,0,stream>>>(xbuf, Wm1, bm1, Wm2, bm2, (float*)d_out, N);
}

// Round 6
// 395.924 us; speedup vs baseline: 1.8901x; 1.2171x over previous
//
#include <hip/hip_runtime.h>
#include <hip/hip_bf16.h>

#define NEG 0.2f

typedef __attribute__((ext_vector_type(8))) short short8v;
typedef __attribute__((ext_vector_type(4))) float f32x4;

static __device__ __forceinline__ float bf2f(unsigned int u16){
  return __uint_as_float(u16 << 16);
}
static __device__ __forceinline__ unsigned short f2bf(float f){
  __hip_bfloat16 h = __float2bfloat16(f);
  return *reinterpret_cast<unsigned short*>(&h);
}

// ---------------- CSR build ----------------
__global__ void k_hist(const int* __restrict__ dst, int* __restrict__ cnt, int E){
  int i = blockIdx.x*blockDim.x + threadIdx.x;
  if (i < E) atomicAdd(&cnt[dst[i]], 1);
}

__global__ void k_scanA(const int* __restrict__ cnt, int* __restrict__ exout,
                        int* __restrict__ bsum, int n){
  __shared__ int sd[256];
  int t = threadIdx.x, b = blockIdx.x;
  int base = b*1024 + t*4;
  int v0 = (base+0<n) ? cnt[base+0] : 0;
  int v1 = (base+1<n) ? cnt[base+1] : 0;
  int v2 = (base+2<n) ? cnt[base+2] : 0;
  int v3 = (base+3<n) ? cnt[base+3] : 0;
  int s = v0+v1+v2+v3;
  sd[t] = s; __syncthreads();
  for (int off=1; off<256; off<<=1){
    int x = (t>=off) ? sd[t-off] : 0;
    __syncthreads();
    sd[t] += x;
    __syncthreads();
  }
  int ex = sd[t] - s;
  if (t==255) bsum[b] = sd[t];
  if (base+0<n) exout[base+0]=ex; ex+=v0;
  if (base+1<n) exout[base+1]=ex; ex+=v1;
  if (base+2<n) exout[base+2]=ex; ex+=v2;
  if (base+3<n) exout[base+3]=ex;
}

__global__ void k_scanB(const int* __restrict__ bsum, int* __restrict__ boff,
                        int* __restrict__ rowptr, int B, int n){
  if (threadIdx.x==0){
    int run=0;
    for (int b=0;b<B;++b){ int t=bsum[b]; boff[b]=run; run+=t; }
    rowptr[n]=run;
  }
}

__global__ void k_scanC(int* __restrict__ rowptr, const int* __restrict__ boff, int n){
  int i = blockIdx.x*blockDim.x + threadIdx.x;
  if (i<n) rowptr[i] += boff[i>>10];
}

__global__ void k_binit(const int* __restrict__ rowptr, int* __restrict__ bfill,
                        int NB, int n){
  int b = blockIdx.x*blockDim.x + threadIdx.x;
  if (b < NB){
    int nb = b << 8; if (nb > n) nb = n;
    bfill[b] = rowptr[nb];
  }
}

#define CHUNK 2048
#define PER_T 8
__global__ __launch_bounds__(256) void k_binpass(
    const int* __restrict__ src, const int* __restrict__ dst,
    int* __restrict__ bfill, unsigned int* __restrict__ pairs, int E, int NB)
{
  __shared__ int lcnt[512];
  __shared__ int lbase[512];
  int t = threadIdx.x;
  int ebase = blockIdx.x * CHUNK;
  for (int j=t; j<NB; j+=256) lcnt[j]=0;
  __syncthreads();
  unsigned int pv[PER_T]; int pb[PER_T];
  #pragma unroll
  for (int k=0;k<PER_T;++k){
    int i = ebase + t + k*256;
    pb[k] = -1;
    if (i < E){
      int d = dst[i];
      int s = src[i];
      pb[k] = d >> 8;
      pv[k] = ((unsigned int)s << 8) | (unsigned int)(d & 255);
      atomicAdd(&lcnt[pb[k]], 1);
    }
  }
  __syncthreads();
  for (int j=t; j<NB; j+=256){
    int c = lcnt[j];
    lbase[j] = c ? atomicAdd(&bfill[j], c) : 0;
    lcnt[j] = 0;
  }
  __syncthreads();
  #pragma unroll
  for (int k=0;k<PER_T;++k){
    if (pb[k] >= 0){
      int ofs = atomicAdd(&lcnt[pb[k]], 1);
      pairs[lbase[pb[k]] + ofs] = pv[k];
    }
  }
}

__global__ __launch_bounds__(256) void k_csr(
    const unsigned int* __restrict__ pairs, const int* __restrict__ rowptr,
    int* __restrict__ csr, int n)
{
  __shared__ int rp[257];
  __shared__ int fil[256];
  int b = blockIdx.x;
  int base = b << 8;
  int t = threadIdx.x;
  int cnt = n - base; if (cnt > 256) cnt = 256;
  for (int j=t; j<=cnt; j+=256) rp[j] = rowptr[base + j];
  if (t < cnt) fil[t] = 0;
  __syncthreads();
  int beg = rp[0], end = rp[cnt];
  for (int i = beg + t; i < end; i += 256){
    unsigned int p = pairs[i];
    int d = (int)(p & 255u);
    int ofs = atomicAdd(&fil[d], 1);
    csr[rp[d] + ofs] = (int)(p >> 8);
  }
}

// ---------------- one-time weight convert: W[k][n] fp32 -> wt[n][k] bf16 ----
__global__ void k_wconv(const float* __restrict__ W, unsigned short* __restrict__ wt){
  int i = blockIdx.x*256 + threadIdx.x;   // 16384 elems
  int k = i >> 7, nn = i & 127;
  wt[nn*128 + k] = f2bf(W[i]);
}

// ---------------- MFMA GEMM (x@W, bf16 in / fp32 acc) + attention dots -----
// block = 256 thr = 4 waves, 64 nodes, N=128 full. wave w = cols [32w,32w+32)
// = head w exactly. A from LDS (bf16, XOR-swizzled), B direct from wt (L1).
__global__ __launch_bounds__(256) void k_gemm_att(
    const float* __restrict__ xin, const unsigned short* __restrict__ wt,
    const float* __restrict__ atts, const float* __restrict__ attd,
    unsigned short* __restrict__ hb, float* __restrict__ as_, float* __restrict__ ad_, int n)
{
  __shared__ __align__(16) unsigned short xls[64*128];
  int t = threadIdx.x;
  int base = blockIdx.x*64;
  int nrem = n - base;
  // stage x -> bf16 LDS, swizzle: kbyte ^= (row&7)<<4 (16B-unit XOR, 8B writes ok)
  const float4* X4 = reinterpret_cast<const float4*>(xin);
  #pragma unroll
  for (int j=0;j<8;++j){
    int i = t + j*256;       // float4 index over 64*32
    int row = i >> 5;
    int cb  = i & 31;
    float4 v = (row < nrem) ? X4[(size_t)(base+row)*32 + cb] : make_float4(0.f,0.f,0.f,0.f);
    unsigned int p0 = (unsigned int)f2bf(v.x) | ((unsigned int)f2bf(v.y)<<16);
    unsigned int p1 = (unsigned int)f2bf(v.z) | ((unsigned int)f2bf(v.w)<<16);
    int addr = row*256 + ((cb*8) ^ ((row&7)<<4));
    *reinterpret_cast<uint2*>(reinterpret_cast<char*>(xls) + addr) = make_uint2(p0,p1);
  }
  __syncthreads();
  int w = t >> 6;
  int l = t & 63;
  int l15 = l & 15, l4 = l >> 4;
  int n0 = w*32;
  // preload all B frags: col n0+nt*16+l15, k = kk*32 + l4*8
  short8v bfr[2][4];
  #pragma unroll
  for (int nt=0;nt<2;++nt){
    const unsigned short* bp = wt + (size_t)(n0 + nt*16 + l15)*128 + l4*8;
    #pragma unroll
    for (int kk=0;kk<4;++kk)
      bfr[nt][kk] = *reinterpret_cast<const short8v*>(bp + kk*32);
  }
  f32x4 acc[4][2];
  #pragma unroll
  for (int mt=0;mt<4;++mt)
    #pragma unroll
    for (int nt=0;nt<2;++nt)
      acc[mt][nt] = (f32x4){0.f,0.f,0.f,0.f};
  #pragma unroll
  for (int kk=0;kk<4;++kk){
    short8v afr[4];
    #pragma unroll
    for (int mt=0;mt<4;++mt){
      int row = mt*16 + l15;
      int addr = row*256 + ((kk*64 + l4*16) ^ ((row&7)<<4));
      afr[mt] = *reinterpret_cast<const short8v*>(reinterpret_cast<char*>(xls) + addr);
    }
    #pragma unroll
    for (int mt=0;mt<4;++mt)
      #pragma unroll
      for (int nt=0;nt<2;++nt)
        acc[mt][nt] = __builtin_amdgcn_mfma_f32_16x16x32_bf16(afr[mt], bfr[nt][kk], acc[mt][nt], 0, 0, 0);
  }
  // attention dots: wave w == head w; reduce over 16-lane col group
  float av0 = atts[n0 + l15],    av1 = atts[n0 + 16 + l15];
  float dv0 = attd[n0 + l15],    dv1 = attd[n0 + 16 + l15];
  #pragma unroll
  for (int mt=0;mt<4;++mt){
    #pragma unroll
    for (int r=0;r<4;++r){
      float ps = acc[mt][0][r]*av0 + acc[mt][1][r]*av1;
      float pd = acc[mt][0][r]*dv0 + acc[mt][1][r]*dv1;
      ps += __shfl_xor(ps,1); ps += __shfl_xor(ps,2);
      ps += __shfl_xor(ps,4); ps += __shfl_xor(ps,8);
      pd += __shfl_xor(pd,1); pd += __shfl_xor(pd,2);
      pd += __shfl_xor(pd,4); pd += __shfl_xor(pd,8);
      int node = base + mt*16 + l4*4 + r;
      if (l15==0 && node < n){
        as_[node*4 + w] = ps;
        ad_[node*4 + w] = pd;
      }
    }
  }
  // h -> bf16 via LDS restage (reuse xls), then coalesced copyout
  __syncthreads();
  #pragma unroll
  for (int mt=0;mt<4;++mt)
    #pragma unroll
    for (int nt=0;nt<2;++nt)
      #pragma unroll
      for (int r=0;r<4;++r){
        int row = mt*16 + l4*4 + r;
        int col = n0 + nt*16 + l15;
        xls[row*128 + col] = f2bf(acc[mt][nt][r]);
      }
  __syncthreads();
  const uint4* xsrc = reinterpret_cast<const uint4*>(xls);
  uint4* hdst = reinterpret_cast<uint4*>(hb + (size_t)base*128);
  #pragma unroll
  for (int j=0;j<4;++j){
    int i = t + j*256;       // uint4 index over 1024 (16 per row)
    int row = i >> 4;
    if (row < nrem) hdst[i] = xsrc[i];
  }
}

// ---------------- per-node softmax-aggregation ----------------
__global__ __launch_bounds__(256) void k_aggr(
    const unsigned short* __restrict__ hb, const float* __restrict__ as_,
    const float* __restrict__ ad_, const int* __restrict__ rowptr,
    const int* __restrict__ csr, const float* __restrict__ bias,
    float* __restrict__ out, int n)
{
  int wid = (int)((blockIdx.x*(size_t)blockDim.x + threadIdx.x) >> 6);
  int lane = threadIdx.x & 63;
  if (wid >= n) return;
  int half = lane >> 5;
  int li   = lane & 31;
  int c0   = li*4;
  int head = li >> 3;
  float adn = ad_[wid*4 + head];
  int beg = rowptr[wid], end = rowptr[wid+1];
  int deg = end - beg;
  float4 acc = make_float4(0.f,0.f,0.f,0.f);
  float z = 0.f;
  int nfull = deg & ~7;
  int lim = beg + nfull;
  int i = beg + half*4;
  int s0=0,s1=0,s2=0,s3=0;
  if (i < lim){ s0=csr[i]; s1=csr[i+1]; s2=csr[i+2]; s3=csr[i+3]; }
  for (; i < lim; ){
    int ni = i + 8;
    int t0=0,t1=0,t2=0,t3=0;
    if (ni < lim){ t0=csr[ni]; t1=csr[ni+1]; t2=csr[ni+2]; t3=csr[ni+3]; }
    float e0 = as_[s0*4+head];
    float e1 = as_[s1*4+head];
    float e2 = as_[s2*4+head];
    float e3 = as_[s3*4+head];
    uint2 p0 = *reinterpret_cast<const uint2*>(hb + (size_t)s0*128 + c0);
    uint2 p1 = *reinterpret_cast<const uint2*>(hb + (size_t)s1*128 + c0);
    uint2 p2 = *reinterpret_cast<const uint2*>(hb + (size_t)s2*128 + c0);
    uint2 p3 = *reinterpret_cast<const uint2*>(hb + (size_t)s3*128 + c0);
    e0 += adn; e1 += adn; e2 += adn; e3 += adn;
    e0 = (e0>0.f)?e0:NEG*e0;
    e1 = (e1>0.f)?e1:NEG*e1;
    e2 = (e2>0.f)?e2:NEG*e2;
    e3 = (e3>0.f)?e3:NEG*e3;
    float x0 = __expf(e0);
    float x1 = __expf(e1);
    float x2 = __expf(e2);
    float x3 = __expf(e3);
    z += (x0+x1)+(x2+x3);
    acc.x = fmaf(x0, bf2f(p0.x & 0xffffu), acc.x);
    acc.y = fmaf(x0, bf2f(p0.x >> 16),     acc.y);
    acc.z = fmaf(x0, bf2f(p0.y & 0xffffu), acc.z);
    acc.w = fmaf(x0, bf2f(p0.y >> 16),     acc.w);
    acc.x = fmaf(x1, bf2f(p1.x & 0xffffu), acc.x);
    acc.y = fmaf(x1, bf2f(p1.x >> 16),     acc.y);
    acc.z = fmaf(x1, bf2f(p1.y & 0xffffu), acc.z);
    acc.w = fmaf(x1, bf2f(p1.y >> 16),     acc.w);
    acc.x = fmaf(x2, bf2f(p2.x & 0xffffu), acc.x);
    acc.y = fmaf(x2, bf2f(p2.x >> 16),     acc.y);
    acc.z = fmaf(x2, bf2f(p2.y & 0xffffu), acc.z);
    acc.w = fmaf(x2, bf2f(p2.y >> 16),     acc.w);
    acc.x = fmaf(x3, bf2f(p3.x & 0xffffu), acc.x);
    acc.y = fmaf(x3, bf2f(p3.x >> 16),     acc.y);
    acc.z = fmaf(x3, bf2f(p3.y & 0xffffu), acc.z);
    acc.w = fmaf(x3, bf2f(p3.y >> 16),     acc.w);
    i = ni; s0=t0; s1=t1; s2=t2; s3=t3;
  }
  for (int j = beg + nfull + half; j < end; j += 2){
    int s = csr[j];
    float e = as_[s*4+head] + adn;
    e = (e>0.f)?e:NEG*e;
    float ee = __expf(e);
    z += ee;
    uint2 pv = *reinterpret_cast<const uint2*>(hb + (size_t)s*128 + c0);
    acc.x = fmaf(ee, bf2f(pv.x & 0xffffu), acc.x);
    acc.y = fmaf(ee, bf2f(pv.x >> 16),     acc.y);
    acc.z = fmaf(ee, bf2f(pv.y & 0xffffu), acc.z);
    acc.w = fmaf(ee, bf2f(pv.y >> 16),     acc.w);
  }
  z     += __shfl_xor(z, 32);
  acc.x += __shfl_xor(acc.x, 32);
  acc.y += __shfl_xor(acc.y, 32);
  acc.z += __shfl_xor(acc.z, 32);
  acc.w += __shfl_xor(acc.w, 32);
  if (half == 0){
    float4 o;
    if (deg > 0){
      float rz = 1.f/z;
      o.x = fmaxf(fmaf(acc.x,rz,bias[c0  ]), 0.f);
      o.y = fmaxf(fmaf(acc.y,rz,bias[c0+1]), 0.f);
      o.z = fmaxf(fmaf(acc.z,rz,bias[c0+2]), 0.f);
      o.w = fmaxf(fmaf(acc.w,rz,bias[c0+3]), 0.f);
    } else {
      o.x = fmaxf(bias[c0  ], 0.f);
      o.y = fmaxf(bias[c0+1], 0.f);
      o.z = fmaxf(bias[c0+2], 0.f);
      o.w = fmaxf(bias[c0+3], 0.f);
    }
    *reinterpret_cast<float4*>(out + (size_t)wid*128 + c0) = o;
  }
}

// ---------------- fused 2-layer MLP ----------------
__global__ __launch_bounds__(256) void k_mlp(
    const float* __restrict__ x, const float* __restrict__ Wm1, const float* __restrict__ bm1,
    const float* __restrict__ Wm2, const float* __restrict__ bm2,
    float* __restrict__ out, int n)
{
  __shared__ float xs[64*129];
  __shared__ float w1s[128*32];
  __shared__ float hs[64*33];
  __shared__ float w2s[32*16];
  __shared__ float b1s[32];
  __shared__ float b2s[16];
  int t = threadIdx.x;
  int base = blockIdx.x*64;
  for (int i=t; i<64*128; i+=256){
    int r=i>>7, c=i&127;
    xs[r*129+c] = (base+r<n) ? x[(size_t)(base+r)*128+c] : 0.f;
  }
  for (int i=t; i<128*32; i+=256) w1s[i]=Wm1[i];
  for (int i=t; i<32*16;  i+=256) w2s[i]=Wm2[i];
  if (t<32) b1s[t]=bm1[t];
  if (t<16) b2s[t]=bm2[t];
  __syncthreads();
  int l = t&63, g = t>>6;
  float hid[8];
  #pragma unroll
  for (int j=0;j<8;++j) hid[j]=0.f;
  for (int k=0;k<128;++k){
    float xk = xs[l*129+k];
    #pragma unroll
    for (int j=0;j<8;++j) hid[j] = fmaf(xk, w1s[k*32 + g*8 + j], hid[j]);
  }
  #pragma unroll
  for (int j=0;j<8;++j) hs[l*33 + g*8 + j] = fmaxf(hid[j] + b1s[g*8+j], 0.f);
  __syncthreads();
  float o[4] = {0.f,0.f,0.f,0.f};
  for (int k=0;k<32;++k){
    float xv = hs[l*33+k];
    #pragma unroll
    for (int j=0;j<4;++j) o[j] = fmaf(xv, w2s[k*16 + g*4 + j], o[j]);
  }
  int node = base + l;
  if (node < n){
    #pragma unroll
    for (int j=0;j<4;++j) out[(size_t)node*16 + g*4 + j] = o[j] + b2s[g*4+j];
  }
}

extern "C" void kernel_launch(void* const* d_in, const int* in_sizes, int n_in,
                              void* d_out, int out_size, void* d_ws, size_t ws_size,
                              hipStream_t stream)
{
  const float* x   = (const float*)d_in[0];
  const int*   ei  = (const int*)  d_in[1];
  const float* W0  = (const float*)d_in[2];
  const float* as0 = (const float*)d_in[3];
  const float* ad0 = (const float*)d_in[4];
  const float* b0  = (const float*)d_in[5];
  const float* W1  = (const float*)d_in[6];
  const float* as1 = (const float*)d_in[7];
  const float* ad1 = (const float*)d_in[8];
  const float* b1  = (const float*)d_in[9];
  const float* Wm1 = (const float*)d_in[10];
  const float* bm1 = (const float*)d_in[11];
  const float* Wm2 = (const float*)d_in[12];
  const float* bm2 = (const float*)d_in[13];
  int N = in_sizes[0]/128;
  int E = in_sizes[1]/2;
  const int* srcI = ei;
  const int* dstI = ei + E;

  char* ws = (char*)d_ws;
  size_t off = 0;
  auto alloc = [&](size_t bytes)->void*{
    void* p = ws + off; off += (bytes + 255) & ~(size_t)255; return p;
  };
  unsigned short* hbuf = (unsigned short*)alloc((size_t)N*128*2);
  float* xbuf  = (float*)alloc((size_t)N*128*4);
  float* asb   = (float*)alloc((size_t)N*4*4);
  float* adb   = (float*)alloc((size_t)N*4*4);
  int* rowptr  = (int*)alloc((size_t)(N+1)*4);
  int* cnt     = (int*)alloc((size_t)N*4);
  int* bfill   = (int*)alloc(4096);
  int* bsum    = (int*)alloc(4096);
  int* boff    = (int*)alloc(4096);
  int* csr     = (int*)alloc((size_t)E*4);
  unsigned int* pairs = (unsigned int*)alloc((size_t)E*4);
  unsigned short* wt0 = (unsigned short*)alloc(128*128*2);
  unsigned short* wt1 = (unsigned short*)alloc(128*128*2);
  (void)ws_size; (void)n_in; (void)out_size;

  int NB = (N + 255) >> 8;
  int B = (N+1023)/1024;
  hipMemsetAsync(cnt, 0, (size_t)N*4, stream);
  int gE = (E+255)/256;
  k_hist   <<<gE,256,0,stream>>>(dstI, cnt, E);
  k_scanA  <<<B, 256,0,stream>>>(cnt, rowptr, bsum, N);
  k_scanB  <<<1, 64, 0,stream>>>(bsum, boff, rowptr, B, N);
  k_scanC  <<<(N+255)/256,256,0,stream>>>(rowptr, boff, N);
  k_binit  <<<(NB+255)/256,256,0,stream>>>(rowptr, bfill, NB, N);
  k_binpass<<<(E+CHUNK-1)/CHUNK,256,0,stream>>>(srcI, dstI, bfill, pairs, E, NB);
  k_csr    <<<NB,256,0,stream>>>(pairs, rowptr, csr, N);
  k_wconv  <<<64,256,0,stream>>>(W0, wt0);
  k_wconv  <<<64,256,0,stream>>>(W1, wt1);

  int gG = (N+63)/64;
  int gA = (int)(((size_t)N*64 + 255)/256);
  k_gemm_att<<<gG,256,0,stream>>>(x,    wt0, as0, ad0, hbuf, asb, adb, N);
  k_aggr    <<<gA,256,0,stream>>>(hbuf, asb, adb, rowptr, csr, b0, xbuf, N);
  k_gemm_att<<<gG,256,0,stream>>>(xbuf, wt1, as1, ad1, hbuf, asb, adb, N);
  k_aggr    <<<gA,256,0,stream>>>(hbuf, asb, adb, rowptr, csr, b1, xbuf, N);
  k_mlp     <<<gG,256,0,stream>>>(xbuf, Wm1, bm1, Wm2, bm2, (float*)d_out, N);
}

// Round 7
// 302.709 us; speedup vs baseline: 2.4721x; 1.3079x over previous
//
#include <hip/hip_runtime.h>
#include <hip/hip_bf16.h>

#define NEG 0.2f

typedef __attribute__((ext_vector_type(8))) short short8v;
typedef __attribute__((ext_vector_type(4))) float f32x4;

static __device__ __forceinline__ float bf2f(unsigned int u16){
  return __uint_as_float(u16 << 16);
}
static __device__ __forceinline__ unsigned short f2bf(float f){
  __hip_bfloat16 h = __float2bfloat16(f);
  return *reinterpret_cast<unsigned short*>(&h);
}

// ---------------- CSR build (bucket = 256 consecutive dst nodes) ----------
#define CHUNK 2048
#define PER_T 8

// count edges per bucket (LDS-aggregated)
__global__ __launch_bounds__(256) void k_bcount(
    const int* __restrict__ dst, int* __restrict__ bcnt, int E, int NB)
{
  __shared__ int lc[512];
  int t = threadIdx.x;
  int ebase = blockIdx.x * CHUNK;
  for (int j=t; j<NB; j+=256) lc[j]=0;
  __syncthreads();
  #pragma unroll
  for (int k=0;k<PER_T;++k){
    int i = ebase + t + k*256;
    if (i < E) atomicAdd(&lc[dst[i] >> 8], 1);
  }
  __syncthreads();
  for (int j=t; j<NB; j+=256){
    int c = lc[j];
    if (c) atomicAdd(&bcnt[j], c);
  }
}

// exclusive scan over NB (<=512) buckets; writes bstart[0..NB], bfill init
__global__ __launch_bounds__(256) void k_bscan(
    const int* __restrict__ bcnt, int* __restrict__ bstart,
    int* __restrict__ bfill, int NB)
{
  __shared__ int sd[256];
  int t = threadIdx.x;
  int i0 = 2*t, i1 = 2*t+1;
  int v0 = (i0<NB) ? bcnt[i0] : 0;
  int v1 = (i1<NB) ? bcnt[i1] : 0;
  int s = v0+v1;
  sd[t]=s; __syncthreads();
  for (int off=1; off<256; off<<=1){
    int x = (t>=off) ? sd[t-off] : 0;
    __syncthreads();
    sd[t] += x;
    __syncthreads();
  }
  int ex = sd[t]-s;
  if (i0<=NB){ bstart[i0]=ex; if(i0<NB) bfill[i0]=ex; }
  ex += v0;
  if (i1<=NB){ bstart[i1]=ex; if(i1<NB) bfill[i1]=ex; }
}

// bin edges into bucket regions of pairs[] (packed: src<<8 | dst&255)
__global__ __launch_bounds__(256) void k_binpass(
    const int* __restrict__ src, const int* __restrict__ dst,
    int* __restrict__ bfill, unsigned int* __restrict__ pairs, int E, int NB)
{
  __shared__ int lcnt[512];
  __shared__ int lbase[512];
  int t = threadIdx.x;
  int ebase = blockIdx.x * CHUNK;
  for (int j=t; j<NB; j+=256) lcnt[j]=0;
  __syncthreads();
  unsigned int pv[PER_T]; int pb[PER_T];
  #pragma unroll
  for (int k=0;k<PER_T;++k){
    int i = ebase + t + k*256;
    pb[k] = -1;
    if (i < E){
      int d = dst[i];
      int s = src[i];
      pb[k] = d >> 8;
      pv[k] = ((unsigned int)s << 8) | (unsigned int)(d & 255);
      atomicAdd(&lcnt[pb[k]], 1);
    }
  }
  __syncthreads();
  for (int j=t; j<NB; j+=256){
    int c = lcnt[j];
    lbase[j] = c ? atomicAdd(&bfill[j], c) : 0;
    lcnt[j] = 0;
  }
  __syncthreads();
  #pragma unroll
  for (int k=0;k<PER_T;++k){
    if (pb[k] >= 0){
      int ofs = atomicAdd(&lcnt[pb[k]], 1);
      pairs[lbase[pb[k]] + ofs] = pv[k];
    }
  }
}

// per bucket: LDS hist+scan -> rowptr slice (coalesced) + csr scatter in-bucket
__global__ __launch_bounds__(256) void k_csr(
    const unsigned int* __restrict__ pairs, const int* __restrict__ bstart,
    int* __restrict__ rowptr, int* __restrict__ csr, int n)
{
  __shared__ int lc[256];
  __shared__ int sd[256];
  __shared__ int rp[257];
  int b = blockIdx.x;
  int base = b << 8;
  int t = threadIdx.x;
  int cnt = n - base; if (cnt > 256) cnt = 256;
  int beg = bstart[b], end = bstart[b+1];
  lc[t]=0; __syncthreads();
  for (int i = beg + t; i < end; i += 256)
    atomicAdd(&lc[pairs[i] & 255u], 1);
  __syncthreads();
  int v = lc[t];
  sd[t]=v; __syncthreads();
  for (int off=1; off<256; off<<=1){
    int x = (t>=off) ? sd[t-off] : 0;
    __syncthreads();
    sd[t] += x;
    __syncthreads();
  }
  rp[t+1] = beg + sd[t];
  if (t==0) rp[0] = beg;
  lc[t] = 0;
  __syncthreads();
  if (t < cnt) rowptr[base + t] = rp[t];
  if (t==0 && base + cnt == n) rowptr[n] = rp[cnt];
  for (int i = beg + t; i < end; i += 256){
    unsigned int p = pairs[i];
    int d = (int)(p & 255u);
    int ofs = atomicAdd(&lc[d], 1);
    csr[rp[d] + ofs] = (int)(p >> 8);
  }
}

// ---------------- weight convert: W[k][n] fp32 -> wt[n][k] bf16 (both) -----
__global__ void k_wconv(const float* __restrict__ W0, const float* __restrict__ W1,
                        unsigned short* __restrict__ wt0, unsigned short* __restrict__ wt1){
  int b = blockIdx.x;
  const float* W = (b < 64) ? W0 : W1;
  unsigned short* wt = (b < 64) ? wt0 : wt1;
  int i = (b & 63)*256 + threadIdx.x;
  int k = i >> 7, nn = i & 127;
  wt[nn*128 + k] = f2bf(W[i]);
}

// ---------------- MFMA GEMM (x@W) + attention dots; h stored bf16 ---------
// block = 4 waves, 64 nodes; wave w = cols [32w,32w+32) = head w.
// IN_BF16: input is packed bf16 (prev layer), else fp32.
template<int IN_BF16>
__global__ __launch_bounds__(256) void k_gemm_att(
    const void* __restrict__ xin_, const unsigned short* __restrict__ wt,
    const float* __restrict__ atts, const float* __restrict__ attd,
    unsigned short* __restrict__ hb, float* __restrict__ as_, float* __restrict__ ad_, int n)
{
  __shared__ __align__(16) unsigned short xls[64*128];
  int t = threadIdx.x;
  int base = blockIdx.x*64;
  int nrem = n - base;
  if (IN_BF16){
    const uint4* Xb = reinterpret_cast<const uint4*>(xin_);   // 8 bf16 each
    #pragma unroll
    for (int j=0;j<4;++j){
      int i = t + j*256;             // 1024 uint4 = 64 rows x 16
      int row = i >> 4, c16 = i & 15;
      uint4 v = (row < nrem) ? Xb[(size_t)(base+row)*16 + c16]
                             : make_uint4(0,0,0,0);
      int addr = row*256 + ((c16*16) ^ ((row&7)<<4));
      *reinterpret_cast<uint4*>(reinterpret_cast<char*>(xls) + addr) = v;
    }
  } else {
    const float4* X4 = reinterpret_cast<const float4*>(xin_);
    #pragma unroll
    for (int j=0;j<8;++j){
      int i = t + j*256;             // 2048 float4 = 64 rows x 32
      int row = i >> 5, cb = i & 31;
      float4 v = (row < nrem) ? X4[(size_t)(base+row)*32 + cb] : make_float4(0.f,0.f,0.f,0.f);
      unsigned int p0 = (unsigned int)f2bf(v.x) | ((unsigned int)f2bf(v.y)<<16);
      unsigned int p1 = (unsigned int)f2bf(v.z) | ((unsigned int)f2bf(v.w)<<16);
      int addr = row*256 + ((cb*8) ^ ((row&7)<<4));
      *reinterpret_cast<uint2*>(reinterpret_cast<char*>(xls) + addr) = make_uint2(p0,p1);
    }
  }
  __syncthreads();
  int w = t >> 6;
  int l = t & 63;
  int l15 = l & 15, l4 = l >> 4;
  int n0 = w*32;
  short8v bfr[2][4];
  #pragma unroll
  for (int nt=0;nt<2;++nt){
    const unsigned short* bp = wt + (size_t)(n0 + nt*16 + l15)*128 + l4*8;
    #pragma unroll
    for (int kk=0;kk<4;++kk)
      bfr[nt][kk] = *reinterpret_cast<const short8v*>(bp + kk*32);
  }
  f32x4 acc[4][2];
  #pragma unroll
  for (int mt=0;mt<4;++mt)
    #pragma unroll
    for (int nt=0;nt<2;++nt)
      acc[mt][nt] = (f32x4){0.f,0.f,0.f,0.f};
  #pragma unroll
  for (int kk=0;kk<4;++kk){
    short8v afr[4];
    #pragma unroll
    for (int mt=0;mt<4;++mt){
      int row = mt*16 + l15;
      int addr = row*256 + ((kk*64 + l4*16) ^ ((row&7)<<4));
      afr[mt] = *reinterpret_cast<const short8v*>(reinterpret_cast<char*>(xls) + addr);
    }
    #pragma unroll
    for (int mt=0;mt<4;++mt)
      #pragma unroll
      for (int nt=0;nt<2;++nt)
        acc[mt][nt] = __builtin_amdgcn_mfma_f32_16x16x32_bf16(afr[mt], bfr[nt][kk], acc[mt][nt], 0, 0, 0);
  }
  float av0 = atts[n0 + l15],    av1 = atts[n0 + 16 + l15];
  float dv0 = attd[n0 + l15],    dv1 = attd[n0 + 16 + l15];
  #pragma unroll
  for (int mt=0;mt<4;++mt){
    #pragma unroll
    for (int r=0;r<4;++r){
      float ps = acc[mt][0][r]*av0 + acc[mt][1][r]*av1;
      float pd = acc[mt][0][r]*dv0 + acc[mt][1][r]*dv1;
      ps += __shfl_xor(ps,1); ps += __shfl_xor(ps,2);
      ps += __shfl_xor(ps,4); ps += __shfl_xor(ps,8);
      pd += __shfl_xor(pd,1); pd += __shfl_xor(pd,2);
      pd += __shfl_xor(pd,4); pd += __shfl_xor(pd,8);
      int node = base + mt*16 + l4*4 + r;
      if (l15==0 && node < n){
        as_[node*4 + w] = ps;
        ad_[node*4 + w] = pd;
      }
    }
  }
  __syncthreads();
  #pragma unroll
  for (int mt=0;mt<4;++mt)
    #pragma unroll
    for (int nt=0;nt<2;++nt)
      #pragma unroll
      for (int r=0;r<4;++r){
        int row = mt*16 + l4*4 + r;
        int col = n0 + nt*16 + l15;
        xls[row*128 + col] = f2bf(acc[mt][nt][r]);
      }
  __syncthreads();
  const uint4* xsrc = reinterpret_cast<const uint4*>(xls);
  uint4* hdst = reinterpret_cast<uint4*>(hb + (size_t)base*128);
  #pragma unroll
  for (int j=0;j<4;++j){
    int i = t + j*256;
    int row = i >> 4;
    if (row < nrem) hdst[i] = xsrc[i];
  }
}

// ---------------- per-node softmax-aggregation (out: packed bf16) ---------
__global__ __launch_bounds__(256) void k_aggr(
    const unsigned short* __restrict__ hb, const float* __restrict__ as_,
    const float* __restrict__ ad_, const int* __restrict__ rowptr,
    const int* __restrict__ csr, const float* __restrict__ bias,
    unsigned short* __restrict__ out, int n)
{
  int wid = (int)((blockIdx.x*(size_t)blockDim.x + threadIdx.x) >> 6);
  int lane = threadIdx.x & 63;
  if (wid >= n) return;
  int half = lane >> 5;
  int li   = lane & 31;
  int c0   = li*4;
  int head = li >> 3;
  float adn = ad_[wid*4 + head];
  int beg = rowptr[wid], end = rowptr[wid+1];
  int deg = end - beg;
  float4 acc = make_float4(0.f,0.f,0.f,0.f);
  float z = 0.f;
  int nfull = deg & ~7;
  int lim = beg + nfull;
  int i = beg + half*4;
  int s0=0,s1=0,s2=0,s3=0;
  if (i < lim){ s0=csr[i]; s1=csr[i+1]; s2=csr[i+2]; s3=csr[i+3]; }
  for (; i < lim; ){
    int ni = i + 8;
    int t0=0,t1=0,t2=0,t3=0;
    if (ni < lim){ t0=csr[ni]; t1=csr[ni+1]; t2=csr[ni+2]; t3=csr[ni+3]; }
    float e0 = as_[s0*4+head];
    float e1 = as_[s1*4+head];
    float e2 = as_[s2*4+head];
    float e3 = as_[s3*4+head];
    uint2 p0 = *reinterpret_cast<const uint2*>(hb + (size_t)s0*128 + c0);
    uint2 p1 = *reinterpret_cast<const uint2*>(hb + (size_t)s1*128 + c0);
    uint2 p2 = *reinterpret_cast<const uint2*>(hb + (size_t)s2*128 + c0);
    uint2 p3 = *reinterpret_cast<const uint2*>(hb + (size_t)s3*128 + c0);
    e0 += adn; e1 += adn; e2 += adn; e3 += adn;
    e0 = (e0>0.f)?e0:NEG*e0;
    e1 = (e1>0.f)?e1:NEG*e1;
    e2 = (e2>0.f)?e2:NEG*e2;
    e3 = (e3>0.f)?e3:NEG*e3;
    float x0 = __expf(e0);
    float x1 = __expf(e1);
    float x2 = __expf(e2);
    float x3 = __expf(e3);
    z += (x0+x1)+(x2+x3);
    acc.x = fmaf(x0, bf2f(p0.x & 0xffffu), acc.x);
    acc.y = fmaf(x0, bf2f(p0.x >> 16),     acc.y);
    acc.z = fmaf(x0, bf2f(p0.y & 0xffffu), acc.z);
    acc.w = fmaf(x0, bf2f(p0.y >> 16),     acc.w);
    acc.x = fmaf(x1, bf2f(p1.x & 0xffffu), acc.x);
    acc.y = fmaf(x1, bf2f(p1.x >> 16),     acc.y);
    acc.z = fmaf(x1, bf2f(p1.y & 0xffffu), acc.z);
    acc.w = fmaf(x1, bf2f(p1.y >> 16),     acc.w);
    acc.x = fmaf(x2, bf2f(p2.x & 0xffffu), acc.x);
    acc.y = fmaf(x2, bf2f(p2.x >> 16),     acc.y);
    acc.z = fmaf(x2, bf2f(p2.y & 0xffffu), acc.z);
    acc.w = fmaf(x2, bf2f(p2.y >> 16),     acc.w);
    acc.x = fmaf(x3, bf2f(p3.x & 0xffffu), acc.x);
    acc.y = fmaf(x3, bf2f(p3.x >> 16),     acc.y);
    acc.z = fmaf(x3, bf2f(p3.y & 0xffffu), acc.z);
    acc.w = fmaf(x3, bf2f(p3.y >> 16),     acc.w);
    i = ni; s0=t0; s1=t1; s2=t2; s3=t3;
  }
  for (int j = beg + nfull + half; j < end; j += 2){
    int s = csr[j];
    float e = as_[s*4+head] + adn;
    e = (e>0.f)?e:NEG*e;
    float ee = __expf(e);
    z += ee;
    uint2 pv = *reinterpret_cast<const uint2*>(hb + (size_t)s*128 + c0);
    acc.x = fmaf(ee, bf2f(pv.x & 0xffffu), acc.x);
    acc.y = fmaf(ee, bf2f(pv.x >> 16),     acc.y);
    acc.z = fmaf(ee, bf2f(pv.y & 0xffffu), acc.z);
    acc.w = fmaf(ee, bf2f(pv.y >> 16),     acc.w);
  }
  z     += __shfl_xor(z, 32);
  acc.x += __shfl_xor(acc.x, 32);
  acc.y += __shfl_xor(acc.y, 32);
  acc.z += __shfl_xor(acc.z, 32);
  acc.w += __shfl_xor(acc.w, 32);
  if (half == 0){
    float4 o;
    if (deg > 0){
      float rz = 1.f/z;
      o.x = fmaxf(fmaf(acc.x,rz,bias[c0  ]), 0.f);
      o.y = fmaxf(fmaf(acc.y,rz,bias[c0+1]), 0.f);
      o.z = fmaxf(fmaf(acc.z,rz,bias[c0+2]), 0.f);
      o.w = fmaxf(fmaf(acc.w,rz,bias[c0+3]), 0.f);
    } else {
      o.x = fmaxf(bias[c0  ], 0.f);
      o.y = fmaxf(bias[c0+1], 0.f);
      o.z = fmaxf(bias[c0+2], 0.f);
      o.w = fmaxf(bias[c0+3], 0.f);
    }
    unsigned int lo = (unsigned int)f2bf(o.x) | ((unsigned int)f2bf(o.y)<<16);
    unsigned int hi = (unsigned int)f2bf(o.z) | ((unsigned int)f2bf(o.w)<<16);
    *reinterpret_cast<uint2*>(out + (size_t)wid*128 + c0) = make_uint2(lo,hi);
  }
}

// ---------------- fused 2-layer MLP (bf16 input) ----------------
__global__ __launch_bounds__(256) void k_mlp(
    const unsigned short* __restrict__ xb, const float* __restrict__ Wm1, const float* __restrict__ bm1,
    const float* __restrict__ Wm2, const float* __restrict__ bm2,
    float* __restrict__ out, int n)
{
  __shared__ float xs[64*129];
  __shared__ float w1s[128*32];
  __shared__ float hs[64*33];
  __shared__ float w2s[32*16];
  __shared__ float b1s[32];
  __shared__ float b2s[16];
  int t = threadIdx.x;
  int base = blockIdx.x*64;
  const uint4* Xb = reinterpret_cast<const uint4*>(xb);
  #pragma unroll
  for (int j=0;j<4;++j){
    int i = t + j*256;               // 1024 uint4 = 64 rows x 16
    int row = i >> 4, seg = i & 15;
    uint4 v = (base+row < n) ? Xb[(size_t)(base+row)*16 + seg] : make_uint4(0,0,0,0);
    float* xp = &xs[row*129 + seg*8];
    xp[0] = bf2f(v.x & 0xffffu); xp[1] = bf2f(v.x >> 16);
    xp[2] = bf2f(v.y & 0xffffu); xp[3] = bf2f(v.y >> 16);
    xp[4] = bf2f(v.z & 0xffffu); xp[5] = bf2f(v.z >> 16);
    xp[6] = bf2f(v.w & 0xffffu); xp[7] = bf2f(v.w >> 16);
  }
  for (int i=t; i<128*32; i+=256) w1s[i]=Wm1[i];
  for (int i=t; i<32*16;  i+=256) w2s[i]=Wm2[i];
  if (t<32) b1s[t]=bm1[t];
  if (t<16) b2s[t]=bm2[t];
  __syncthreads();
  int l = t&63, g = t>>6;
  float hid[8];
  #pragma unroll
  for (int j=0;j<8;++j) hid[j]=0.f;
  for (int k=0;k<128;++k){
    float xk = xs[l*129+k];
    #pragma unroll
    for (int j=0;j<8;++j) hid[j] = fmaf(xk, w1s[k*32 + g*8 + j], hid[j]);
  }
  #pragma unroll
  for (int j=0;j<8;++j) hs[l*33 + g*8 + j] = fmaxf(hid[j] + b1s[g*8+j], 0.f);
  __syncthreads();
  float o[4] = {0.f,0.f,0.f,0.f};
  for (int k=0;k<32;++k){
    float xv = hs[l*33+k];
    #pragma unroll
    for (int j=0;j<4;++j) o[j] = fmaf(xv, w2s[k*16 + g*4 + j], o[j]);
  }
  int node = base + l;
  if (node < n){
    #pragma unroll
    for (int j=0;j<4;++j) out[(size_t)node*16 + g*4 + j] = o[j] + b2s[g*4+j];
  }
}

extern "C" void kernel_launch(void* const* d_in, const int* in_sizes, int n_in,
                              void* d_out, int out_size, void* d_ws, size_t ws_size,
                              hipStream_t stream)
{
  const float* x   = (const float*)d_in[0];
  const int*   ei  = (const int*)  d_in[1];
  const float* W0  = (const float*)d_in[2];
  const float* as0 = (const float*)d_in[3];
  const float* ad0 = (const float*)d_in[4];
  const float* b0  = (const float*)d_in[5];
  const float* W1  = (const float*)d_in[6];
  const float* as1 = (const float*)d_in[7];
  const float* ad1 = (const float*)d_in[8];
  const float* b1  = (const float*)d_in[9];
  const float* Wm1 = (const float*)d_in[10];
  const float* bm1 = (const float*)d_in[11];
  const float* Wm2 = (const float*)d_in[12];
  const float* bm2 = (const float*)d_in[13];
  int N = in_sizes[0]/128;
  int E = in_sizes[1]/2;
  const int* srcI = ei;
  const int* dstI = ei + E;

  char* ws = (char*)d_ws;
  size_t off = 0;
  auto alloc = [&](size_t bytes)->void*{
    void* p = ws + off; off += (bytes + 255) & ~(size_t)255; return p;
  };
  unsigned short* hbuf = (unsigned short*)alloc((size_t)N*128*2);
  unsigned short* xbuf = (unsigned short*)alloc((size_t)N*128*2);
  float* asb   = (float*)alloc((size_t)N*4*4);
  float* adb   = (float*)alloc((size_t)N*4*4);
  int* rowptr  = (int*)alloc((size_t)(N+1)*4);
  int* bcnt    = (int*)alloc(2048);
  int* bstart  = (int*)alloc(2052);
  int* bfill   = (int*)alloc(2048);
  int* csr     = (int*)alloc((size_t)E*4);
  unsigned int* pairs = (unsigned int*)alloc((size_t)E*4);
  unsigned short* wt0 = (unsigned short*)alloc(128*128*2);
  unsigned short* wt1 = (unsigned short*)alloc(128*128*2);
  (void)ws_size; (void)n_in; (void)out_size;

  int NB = (N + 255) >> 8;   // <=512
  int gC = (E + CHUNK - 1) / CHUNK;
  hipMemsetAsync(bcnt, 0, 2048, stream);
  k_bcount <<<gC,256,0,stream>>>(dstI, bcnt, E, NB);
  k_bscan  <<<1, 256,0,stream>>>(bcnt, bstart, bfill, NB);
  k_binpass<<<gC,256,0,stream>>>(srcI, dstI, bfill, pairs, E, NB);
  k_csr    <<<NB,256,0,stream>>>(pairs, bstart, rowptr, csr, N);
  k_wconv  <<<128,256,0,stream>>>(W0, W1, wt0, wt1);

  int gG = (N+63)/64;
  int gA = (int)(((size_t)N*64 + 255)/256);
  k_gemm_att<0><<<gG,256,0,stream>>>(x,    wt0, as0, ad0, hbuf, asb, adb, N);
  k_aggr       <<<gA,256,0,stream>>>(hbuf, asb, adb, rowptr, csr, b0, xbuf, N);
  k_gemm_att<1><<<gG,256,0,stream>>>(xbuf, wt1, as1, ad1, hbuf, asb, adb, N);
  k_aggr       <<<gA,256,0,stream>>>(hbuf, asb, adb, rowptr, csr, b1, xbuf, N);
  k_mlp        <<<gG,256,0,stream>>>(xbuf, Wm1, bm1, Wm2, bm2, (float*)d_out, N);
}

// Round 8
// 286.933 us; speedup vs baseline: 2.6081x; 1.0550x over previous
//
#include <hip/hip_runtime.h>
#include <hip/hip_bf16.h>

#define NEG 0.2f

typedef __attribute__((ext_vector_type(8))) short short8v;
typedef __attribute__((ext_vector_type(4))) float f32x4;

static __device__ __forceinline__ float bf2f(unsigned int u16){
  return __uint_as_float(u16 << 16);
}
static __device__ __forceinline__ unsigned short f2bf(float f){
  __hip_bfloat16 h = __float2bfloat16(f);
  return *reinterpret_cast<unsigned short*>(&h);
}

#define CHUNK 2048
#define PER_T 8

// ---------------- device bodies ----------------

// count edges per bucket (LDS-aggregated); blk indexes the edge chunk
static __device__ __forceinline__ void bcount_body(
    const int* __restrict__ dst, int* __restrict__ bcnt, int E, int NB,
    int blk, int* lc)
{
  int t = threadIdx.x;
  int ebase = blk * CHUNK;
  for (int j=t; j<NB; j+=256) lc[j]=0;
  __syncthreads();
  #pragma unroll
  for (int k=0;k<PER_T;++k){
    int i = ebase + t + k*256;
    if (i < E) atomicAdd(&lc[dst[i] >> 8], 1);
  }
  __syncthreads();
  for (int j=t; j<NB; j+=256){
    int c = lc[j];
    if (c) atomicAdd(&bcnt[j], c);
  }
}

// bin edges into bucket regions of pairs[] (packed: src<<8 | dst&255)
static __device__ __forceinline__ void binpass_body(
    const int* __restrict__ src, const int* __restrict__ dst,
    int* __restrict__ bfill, unsigned int* __restrict__ pairs, int E, int NB,
    int blk, int* lcnt, int* lbase)
{
  int t = threadIdx.x;
  int ebase = blk * CHUNK;
  for (int j=t; j<NB; j+=256) lcnt[j]=0;
  __syncthreads();
  unsigned int pv[PER_T]; int pb[PER_T];
  #pragma unroll
  for (int k=0;k<PER_T;++k){
    int i = ebase + t + k*256;
    pb[k] = -1;
    if (i < E){
      int d = dst[i];
      int s = src[i];
      pb[k] = d >> 8;
      pv[k] = ((unsigned int)s << 8) | (unsigned int)(d & 255);
      atomicAdd(&lcnt[pb[k]], 1);
    }
  }
  __syncthreads();
  for (int j=t; j<NB; j+=256){
    int c = lcnt[j];
    lbase[j] = c ? atomicAdd(&bfill[j], c) : 0;
    lcnt[j] = 0;
  }
  __syncthreads();
  #pragma unroll
  for (int k=0;k<PER_T;++k){
    if (pb[k] >= 0){
      int ofs = atomicAdd(&lcnt[pb[k]], 1);
      pairs[lbase[pb[k]] + ofs] = pv[k];
    }
  }
}

// MFMA GEMM (x@W) + attention dots; h stored bf16. blk indexes 64-node tile.
template<int IN_BF16>
static __device__ __forceinline__ void gemm_att_body(
    const void* __restrict__ xin_, const unsigned short* __restrict__ wt,
    const float* __restrict__ atts, const float* __restrict__ attd,
    unsigned short* __restrict__ hb, float* __restrict__ as_, float* __restrict__ ad_,
    int n, int blk, unsigned short* xls)
{
  int t = threadIdx.x;
  int base = blk*64;
  int nrem = n - base;
  if (IN_BF16){
    const uint4* Xb = reinterpret_cast<const uint4*>(xin_);
    #pragma unroll
    for (int j=0;j<4;++j){
      int i = t + j*256;             // 1024 uint4 = 64 rows x 16
      int row = i >> 4, c16 = i & 15;
      uint4 v = (row < nrem) ? Xb[(size_t)(base+row)*16 + c16]
                             : make_uint4(0,0,0,0);
      int addr = row*256 + ((c16*16) ^ ((row&7)<<4));
      *reinterpret_cast<uint4*>(reinterpret_cast<char*>(xls) + addr) = v;
    }
  } else {
    const float4* X4 = reinterpret_cast<const float4*>(xin_);
    #pragma unroll
    for (int j=0;j<8;++j){
      int i = t + j*256;             // 2048 float4 = 64 rows x 32
      int row = i >> 5, cb = i & 31;
      float4 v = (row < nrem) ? X4[(size_t)(base+row)*32 + cb] : make_float4(0.f,0.f,0.f,0.f);
      unsigned int p0 = (unsigned int)f2bf(v.x) | ((unsigned int)f2bf(v.y)<<16);
      unsigned int p1 = (unsigned int)f2bf(v.z) | ((unsigned int)f2bf(v.w)<<16);
      int addr = row*256 + ((cb*8) ^ ((row&7)<<4));
      *reinterpret_cast<uint2*>(reinterpret_cast<char*>(xls) + addr) = make_uint2(p0,p1);
    }
  }
  __syncthreads();
  int w = t >> 6;
  int l = t & 63;
  int l15 = l & 15, l4 = l >> 4;
  int n0 = w*32;
  short8v bfr[2][4];
  #pragma unroll
  for (int nt=0;nt<2;++nt){
    const unsigned short* bp = wt + (size_t)(n0 + nt*16 + l15)*128 + l4*8;
    #pragma unroll
    for (int kk=0;kk<4;++kk)
      bfr[nt][kk] = *reinterpret_cast<const short8v*>(bp + kk*32);
  }
  f32x4 acc[4][2];
  #pragma unroll
  for (int mt=0;mt<4;++mt)
    #pragma unroll
    for (int nt=0;nt<2;++nt)
      acc[mt][nt] = (f32x4){0.f,0.f,0.f,0.f};
  #pragma unroll
  for (int kk=0;kk<4;++kk){
    short8v afr[4];
    #pragma unroll
    for (int mt=0;mt<4;++mt){
      int row = mt*16 + l15;
      int addr = row*256 + ((kk*64 + l4*16) ^ ((row&7)<<4));
      afr[mt] = *reinterpret_cast<const short8v*>(reinterpret_cast<char*>(xls) + addr);
    }
    #pragma unroll
    for (int mt=0;mt<4;++mt)
      #pragma unroll
      for (int nt=0;nt<2;++nt)
        acc[mt][nt] = __builtin_amdgcn_mfma_f32_16x16x32_bf16(afr[mt], bfr[nt][kk], acc[mt][nt], 0, 0, 0);
  }
  float av0 = atts[n0 + l15],    av1 = atts[n0 + 16 + l15];
  float dv0 = attd[n0 + l15],    dv1 = attd[n0 + 16 + l15];
  #pragma unroll
  for (int mt=0;mt<4;++mt){
    #pragma unroll
    for (int r=0;r<4;++r){
      float ps = acc[mt][0][r]*av0 + acc[mt][1][r]*av1;
      float pd = acc[mt][0][r]*dv0 + acc[mt][1][r]*dv1;
      ps += __shfl_xor(ps,1); ps += __shfl_xor(ps,2);
      ps += __shfl_xor(ps,4); ps += __shfl_xor(ps,8);
      pd += __shfl_xor(pd,1); pd += __shfl_xor(pd,2);
      pd += __shfl_xor(pd,4); pd += __shfl_xor(pd,8);
      int node = base + mt*16 + l4*4 + r;
      if (l15==0 && node < n){
        as_[node*4 + w] = ps;
        ad_[node*4 + w] = pd;
      }
    }
  }
  __syncthreads();
  #pragma unroll
  for (int mt=0;mt<4;++mt)
    #pragma unroll
    for (int nt=0;nt<2;++nt)
      #pragma unroll
      for (int r=0;r<4;++r){
        int row = mt*16 + l4*4 + r;
        int col = n0 + nt*16 + l15;
        xls[row*128 + col] = f2bf(acc[mt][nt][r]);
      }
  __syncthreads();
  const uint4* xsrc = reinterpret_cast<const uint4*>(xls);
  uint4* hdst = reinterpret_cast<uint4*>(hb + (size_t)base*128);
  #pragma unroll
  for (int j=0;j<4;++j){
    int i = t + j*256;
    int row = i >> 4;
    if (row < nrem) hdst[i] = xsrc[i];
  }
}

// ---------------- fused launches ----------------

// blocks [0,128): wconv; blocks [128, 128+gC): bcount
__global__ __launch_bounds__(256) void k_wconv_bcount(
    const float* __restrict__ W0, const float* __restrict__ W1,
    unsigned short* __restrict__ wt0, unsigned short* __restrict__ wt1,
    const int* __restrict__ dst, int* __restrict__ bcnt, int E, int NB)
{
  __shared__ int lc[512];
  int b = blockIdx.x;
  if (b < 128){
    const float* W = (b < 64) ? W0 : W1;
    unsigned short* wt = (b < 64) ? wt0 : wt1;
    int i = (b & 63)*256 + threadIdx.x;
    int k = i >> 7, nn = i & 127;
    wt[nn*128 + k] = f2bf(W[i]);
  } else {
    bcount_body(dst, bcnt, E, NB, b - 128, lc);
  }
}

// exclusive scan over NB (<=512) buckets
__global__ __launch_bounds__(256) void k_bscan(
    const int* __restrict__ bcnt, int* __restrict__ bstart,
    int* __restrict__ bfill, int NB)
{
  __shared__ int sd[256];
  int t = threadIdx.x;
  int i0 = 2*t, i1 = 2*t+1;
  int v0 = (i0<NB) ? bcnt[i0] : 0;
  int v1 = (i1<NB) ? bcnt[i1] : 0;
  int s = v0+v1;
  sd[t]=s; __syncthreads();
  for (int off=1; off<256; off<<=1){
    int x = (t>=off) ? sd[t-off] : 0;
    __syncthreads();
    sd[t] += x;
    __syncthreads();
  }
  int ex = sd[t]-s;
  if (i0<=NB){ bstart[i0]=ex; if(i0<NB) bfill[i0]=ex; }
  ex += v0;
  if (i1<=NB){ bstart[i1]=ex; if(i1<NB) bfill[i1]=ex; }
}

// blocks [0,nG): gemm layer-1 (fp32 in); blocks [nG, nG+gC): binpass
__global__ __launch_bounds__(256) void k_gemm1_binpass(
    const float* __restrict__ xin, const unsigned short* __restrict__ wt,
    const float* __restrict__ atts, const float* __restrict__ attd,
    unsigned short* __restrict__ hb, float* __restrict__ as_, float* __restrict__ ad_,
    int n, int nG,
    const int* __restrict__ src, const int* __restrict__ dst,
    int* __restrict__ bfill, unsigned int* __restrict__ pairs, int E, int NB)
{
  __shared__ __align__(16) unsigned short xls[64*128];
  __shared__ int lcnt[512];
  __shared__ int lbase[512];
  int b = blockIdx.x;
  if (b < nG){
    gemm_att_body<0>(xin, wt, atts, attd, hb, as_, ad_, n, b, xls);
  } else {
    binpass_body(src, dst, bfill, pairs, E, NB, b - nG, lcnt, lbase);
  }
}

// layer-2 GEMM (bf16 in)
__global__ __launch_bounds__(256) void k_gemm2(
    const unsigned short* __restrict__ xin, const unsigned short* __restrict__ wt,
    const float* __restrict__ atts, const float* __restrict__ attd,
    unsigned short* __restrict__ hb, float* __restrict__ as_, float* __restrict__ ad_, int n)
{
  __shared__ __align__(16) unsigned short xls[64*128];
  gemm_att_body<1>(xin, wt, atts, attd, hb, as_, ad_, n, blockIdx.x, xls);
}

// per bucket: LDS hist+scan -> rowptr slice + csr scatter in-bucket
__global__ __launch_bounds__(256) void k_csr(
    const unsigned int* __restrict__ pairs, const int* __restrict__ bstart,
    int* __restrict__ rowptr, int* __restrict__ csr, int n)
{
  __shared__ int lc[256];
  __shared__ int sd[256];
  __shared__ int rp[257];
  int b = blockIdx.x;
  int base = b << 8;
  int t = threadIdx.x;
  int cnt = n - base; if (cnt > 256) cnt = 256;
  int beg = bstart[b], end = bstart[b+1];
  lc[t]=0; __syncthreads();
  for (int i = beg + t; i < end; i += 256)
    atomicAdd(&lc[pairs[i] & 255u], 1);
  __syncthreads();
  int v = lc[t];
  sd[t]=v; __syncthreads();
  for (int off=1; off<256; off<<=1){
    int x = (t>=off) ? sd[t-off] : 0;
    __syncthreads();
    sd[t] += x;
    __syncthreads();
  }
  rp[t+1] = beg + sd[t];
  if (t==0) rp[0] = beg;
  lc[t] = 0;
  __syncthreads();
  if (t < cnt) rowptr[base + t] = rp[t];
  if (t==0 && base + cnt == n) rowptr[n] = rp[cnt];
  for (int i = beg + t; i < end; i += 256){
    unsigned int p = pairs[i];
    int d = (int)(p & 255u);
    int ofs = atomicAdd(&lc[d], 1);
    csr[rp[d] + ofs] = (int)(p >> 8);
  }
}

// ---------------- per-node softmax-aggregation (out: packed bf16) ---------
__global__ __launch_bounds__(256) void k_aggr(
    const unsigned short* __restrict__ hb, const float* __restrict__ as_,
    const float* __restrict__ ad_, const int* __restrict__ rowptr,
    const int* __restrict__ csr, const float* __restrict__ bias,
    unsigned short* __restrict__ out, int n)
{
  int wid = (int)((blockIdx.x*(size_t)blockDim.x + threadIdx.x) >> 6);
  int lane = threadIdx.x & 63;
  if (wid >= n) return;
  int half = lane >> 5;
  int li   = lane & 31;
  int c0   = li*4;
  int head = li >> 3;
  float adn = ad_[wid*4 + head];
  int beg = rowptr[wid], end = rowptr[wid+1];
  int deg = end - beg;
  float4 acc = make_float4(0.f,0.f,0.f,0.f);
  float z = 0.f;
  int nfull = deg & ~7;
  int lim = beg + nfull;
  int i = beg + half*4;
  int s0=0,s1=0,s2=0,s3=0;
  if (i < lim){ s0=csr[i]; s1=csr[i+1]; s2=csr[i+2]; s3=csr[i+3]; }
  for (; i < lim; ){
    int ni = i + 8;
    int t0=0,t1=0,t2=0,t3=0;
    if (ni < lim){ t0=csr[ni]; t1=csr[ni+1]; t2=csr[ni+2]; t3=csr[ni+3]; }
    float e0 = as_[s0*4+head];
    float e1 = as_[s1*4+head];
    float e2 = as_[s2*4+head];
    float e3 = as_[s3*4+head];
    uint2 p0 = *reinterpret_cast<const uint2*>(hb + (size_t)s0*128 + c0);
    uint2 p1 = *reinterpret_cast<const uint2*>(hb + (size_t)s1*128 + c0);
    uint2 p2 = *reinterpret_cast<const uint2*>(hb + (size_t)s2*128 + c0);
    uint2 p3 = *reinterpret_cast<const uint2*>(hb + (size_t)s3*128 + c0);
    e0 += adn; e1 += adn; e2 += adn; e3 += adn;
    e0 = (e0>0.f)?e0:NEG*e0;
    e1 = (e1>0.f)?e1:NEG*e1;
    e2 = (e2>0.f)?e2:NEG*e2;
    e3 = (e3>0.f)?e3:NEG*e3;
    float x0 = __expf(e0);
    float x1 = __expf(e1);
    float x2 = __expf(e2);
    float x3 = __expf(e3);
    z += (x0+x1)+(x2+x3);
    acc.x = fmaf(x0, bf2f(p0.x & 0xffffu), acc.x);
    acc.y = fmaf(x0, bf2f(p0.x >> 16),     acc.y);
    acc.z = fmaf(x0, bf2f(p0.y & 0xffffu), acc.z);
    acc.w = fmaf(x0, bf2f(p0.y >> 16),     acc.w);
    acc.x = fmaf(x1, bf2f(p1.x & 0xffffu), acc.x);
    acc.y = fmaf(x1, bf2f(p1.x >> 16),     acc.y);
    acc.z = fmaf(x1, bf2f(p1.y & 0xffffu), acc.z);
    acc.w = fmaf(x1, bf2f(p1.y >> 16),     acc.w);
    acc.x = fmaf(x2, bf2f(p2.x & 0xffffu), acc.x);
    acc.y = fmaf(x2, bf2f(p2.x >> 16),     acc.y);
    acc.z = fmaf(x2, bf2f(p2.y & 0xffffu), acc.z);
    acc.w = fmaf(x2, bf2f(p2.y >> 16),     acc.w);
    acc.x = fmaf(x3, bf2f(p3.x & 0xffffu), acc.x);
    acc.y = fmaf(x3, bf2f(p3.x >> 16),     acc.y);
    acc.z = fmaf(x3, bf2f(p3.y & 0xffffu), acc.z);
    acc.w = fmaf(x3, bf2f(p3.y >> 16),     acc.w);
    i = ni; s0=t0; s1=t1; s2=t2; s3=t3;
  }
  for (int j = beg + nfull + half; j < end; j += 2){
    int s = csr[j];
    float e = as_[s*4+head] + adn;
    e = (e>0.f)?e:NEG*e;
    float ee = __expf(e);
    z += ee;
    uint2 pv = *reinterpret_cast<const uint2*>(hb + (size_t)s*128 + c0);
    acc.x = fmaf(ee, bf2f(pv.x & 0xffffu), acc.x);
    acc.y = fmaf(ee, bf2f(pv.x >> 16),     acc.y);
    acc.z = fmaf(ee, bf2f(pv.y & 0xffffu), acc.z);
    acc.w = fmaf(ee, bf2f(pv.y >> 16),     acc.w);
  }
  z     += __shfl_xor(z, 32);
  acc.x += __shfl_xor(acc.x, 32);
  acc.y += __shfl_xor(acc.y, 32);
  acc.z += __shfl_xor(acc.z, 32);
  acc.w += __shfl_xor(acc.w, 32);
  if (half == 0){
    float4 o;
    if (deg > 0){
      float rz = 1.f/z;
      o.x = fmaxf(fmaf(acc.x,rz,bias[c0  ]), 0.f);
      o.y = fmaxf(fmaf(acc.y,rz,bias[c0+1]), 0.f);
      o.z = fmaxf(fmaf(acc.z,rz,bias[c0+2]), 0.f);
      o.w = fmaxf(fmaf(acc.w,rz,bias[c0+3]), 0.f);
    } else {
      o.x = fmaxf(bias[c0  ], 0.f);
      o.y = fmaxf(bias[c0+1], 0.f);
      o.z = fmaxf(bias[c0+2], 0.f);
      o.w = fmaxf(bias[c0+3], 0.f);
    }
    unsigned int lo = (unsigned int)f2bf(o.x) | ((unsigned int)f2bf(o.y)<<16);
    unsigned int hi = (unsigned int)f2bf(o.z) | ((unsigned int)f2bf(o.w)<<16);
    *reinterpret_cast<uint2*>(out + (size_t)wid*128 + c0) = make_uint2(lo,hi);
  }
}

// ---------------- fused 2-layer MLP (bf16 input) ----------------
__global__ __launch_bounds__(256) void k_mlp(
    const unsigned short* __restrict__ xb, const float* __restrict__ Wm1, const float* __restrict__ bm1,
    const float* __restrict__ Wm2, const float* __restrict__ bm2,
    float* __restrict__ out, int n)
{
  __shared__ float xs[64*129];
  __shared__ float w1s[128*32];
  __shared__ float hs[64*33];
  __shared__ float w2s[32*16];
  __shared__ float b1s[32];
  __shared__ float b2s[16];
  int t = threadIdx.x;
  int base = blockIdx.x*64;
  const uint4* Xb = reinterpret_cast<const uint4*>(xb);
  #pragma unroll
  for (int j=0;j<4;++j){
    int i = t + j*256;
    int row = i >> 4, seg = i & 15;
    uint4 v = (base+row < n) ? Xb[(size_t)(base+row)*16 + seg] : make_uint4(0,0,0,0);
    float* xp = &xs[row*129 + seg*8];
    xp[0] = bf2f(v.x & 0xffffu); xp[1] = bf2f(v.x >> 16);
    xp[2] = bf2f(v.y & 0xffffu); xp[3] = bf2f(v.y >> 16);
    xp[4] = bf2f(v.z & 0xffffu); xp[5] = bf2f(v.z >> 16);
    xp[6] = bf2f(v.w & 0xffffu); xp[7] = bf2f(v.w >> 16);
  }
  for (int i=t; i<128*32; i+=256) w1s[i]=Wm1[i];
  for (int i=t; i<32*16;  i+=256) w2s[i]=Wm2[i];
  if (t<32) b1s[t]=bm1[t];
  if (t<16) b2s[t]=bm2[t];
  __syncthreads();
  int l = t&63, g = t>>6;
  float hid[8];
  #pragma unroll
  for (int j=0;j<8;++j) hid[j]=0.f;
  for (int k=0;k<128;++k){
    float xk = xs[l*129+k];
    #pragma unroll
    for (int j=0;j<8;++j) hid[j] = fmaf(xk, w1s[k*32 + g*8 + j], hid[j]);
  }
  #pragma unroll
  for (int j=0;j<8;++j) hs[l*33 + g*8 + j] = fmaxf(hid[j] + b1s[g*8+j], 0.f);
  __syncthreads();
  float o[4] = {0.f,0.f,0.f,0.f};
  for (int k=0;k<32;++k){
    float xv = hs[l*33+k];
    #pragma unroll
    for (int j=0;j<4;++j) o[j] = fmaf(xv, w2s[k*16 + g*4 + j], o[j]);
  }
  int node = base + l;
  if (node < n){
    #pragma unroll
    for (int j=0;j<4;++j) out[(size_t)node*16 + g*4 + j] = o[j] + b2s[g*4+j];
  }
}

extern "C" void kernel_launch(void* const* d_in, const int* in_sizes, int n_in,
                              void* d_out, int out_size, void* d_ws, size_t ws_size,
                              hipStream_t stream)
{
  const float* x   = (const float*)d_in[0];
  const int*   ei  = (const int*)  d_in[1];
  const float* W0  = (const float*)d_in[2];
  const float* as0 = (const float*)d_in[3];
  const float* ad0 = (const float*)d_in[4];
  const float* b0  = (const float*)d_in[5];
  const float* W1  = (const float*)d_in[6];
  const float* as1 = (const float*)d_in[7];
  const float* ad1 = (const float*)d_in[8];
  const float* b1  = (const float*)d_in[9];
  const float* Wm1 = (const float*)d_in[10];
  const float* bm1 = (const float*)d_in[11];
  const float* Wm2 = (const float*)d_in[12];
  const float* bm2 = (const float*)d_in[13];
  int N = in_sizes[0]/128;
  int E = in_sizes[1]/2;
  const int* srcI = ei;
  const int* dstI = ei + E;

  char* ws = (char*)d_ws;
  size_t off = 0;
  auto alloc = [&](size_t bytes)->void*{
    void* p = ws + off; off += (bytes + 255) & ~(size_t)255; return p;
  };
  unsigned short* hbuf = (unsigned short*)alloc((size_t)N*128*2);
  unsigned short* xbuf = (unsigned short*)alloc((size_t)N*128*2);
  float* asb   = (float*)alloc((size_t)N*4*4);
  float* adb   = (float*)alloc((size_t)N*4*4);
  int* rowptr  = (int*)alloc((size_t)(N+1)*4);
  int* bcnt    = (int*)alloc(2048);
  int* bstart  = (int*)alloc(2052);
  int* bfill   = (int*)alloc(2048);
  int* csr     = (int*)alloc((size_t)E*4);
  unsigned int* pairs = (unsigned int*)alloc((size_t)E*4);
  unsigned short* wt0 = (unsigned short*)alloc(128*128*2);
  unsigned short* wt1 = (unsigned short*)alloc(128*128*2);
  (void)ws_size; (void)n_in; (void)out_size;

  int NB = (N + 255) >> 8;   // <=512
  int gC = (E + CHUNK - 1) / CHUNK;
  int gG = (N+63)/64;
  int gA = (int)(((size_t)N*64 + 255)/256);

  hipMemsetAsync(bcnt, 0, 2048, stream);
  k_wconv_bcount<<<128+gC,256,0,stream>>>(W0, W1, wt0, wt1, dstI, bcnt, E, NB);
  k_bscan       <<<1,256,0,stream>>>(bcnt, bstart, bfill, NB);
  k_gemm1_binpass<<<gG+gC,256,0,stream>>>(x, wt0, as0, ad0, hbuf, asb, adb, N, gG,
                                          srcI, dstI, bfill, pairs, E, NB);
  k_csr         <<<NB,256,0,stream>>>(pairs, bstart, rowptr, csr, N);
  k_aggr        <<<gA,256,0,stream>>>(hbuf, asb, adb, rowptr, csr, b0, xbuf, N);
  k_gemm2       <<<gG,256,0,stream>>>(xbuf, wt1, as1, ad1, hbuf, asb, adb, N);
  k_aggr        <<<gA,256,0,stream>>>(hbuf, asb, adb, rowptr, csr, b1, xbuf, N);
  k_mlp         <<<gG,256,0,stream>>>(xbuf, Wm1, bm1, Wm2, bm2, (float*)d_out, N);
}